// Round 6
// baseline (706.331 us; speedup 1.0000x reference)
//
#include <hip/hip_runtime.h>
#include <hip/hip_fp16.h>
#include <math.h>

#define NN 50000
#define NE 800000
#define ETOT (NE + NN)
#define INC 128
#define F1 64
#define NH 8
#define OC 16
#define NEG 0.2f
#define NB 196   // ceil(NN/256)

__device__ __forceinline__ float leaky(float x){ return x > 0.f ? x : NEG * x; }

// edge_index arrives as int32 (harness converts integer inputs to int32)
__device__ __forceinline__ void getsd(const int* __restrict__ ei, int e, int& s, int& d){
    if (e < NE){ s = ei[e]; d = ei[NE + e]; }
    else { s = e - NE; d = s; }   // self-loops appended
}

// ---------------- CSR build ----------------

__global__ void hist(const int* __restrict__ ei, int* __restrict__ deg){
    int e = blockIdx.x*256 + threadIdx.x;
    if (e >= ETOT) return;
    int d = (e < NE) ? ei[NE + e] : e - NE;
    atomicAdd(&deg[d], 1);
}

__global__ __launch_bounds__(256) void block_sum(const int* __restrict__ deg, int* __restrict__ bsum){
    int i = blockIdx.x*256 + threadIdx.x;
    int v = (i < NN) ? deg[i] : 0;
    #pragma unroll
    for (int off = 1; off < 64; off <<= 1) v += __shfl_xor(v, off);
    __shared__ int ws[4];
    if ((threadIdx.x & 63) == 0) ws[threadIdx.x >> 6] = v;
    __syncthreads();
    if (threadIdx.x == 0) bsum[blockIdx.x] = ws[0] + ws[1] + ws[2] + ws[3];
}

__global__ __launch_bounds__(256) void scan_bsum(const int* __restrict__ bsum, int* __restrict__ boff){
    __shared__ int s[256];
    int t = threadIdx.x;
    int v = (t < NB) ? bsum[t] : 0;
    s[t] = v; __syncthreads();
    for (int off = 1; off < 256; off <<= 1){
        int u = (t >= off) ? s[t - off] : 0;
        __syncthreads();
        s[t] += u;
        __syncthreads();
    }
    if (t < NB) boff[t] = s[t] - v;   // exclusive
}

__global__ __launch_bounds__(256) void scan_final(const int* __restrict__ deg, const int* __restrict__ boff,
        int* __restrict__ rowstart, int* __restrict__ cursor){
    int t = threadIdx.x, lane = t & 63, w = t >> 6;
    int i = blockIdx.x*256 + t;
    int orig = (i < NN) ? deg[i] : 0;
    int v = orig;
    #pragma unroll
    for (int off = 1; off < 64; off <<= 1){
        int u = __shfl_up(v, off);
        if (lane >= off) v += u;
    }
    __shared__ int ws[4];
    if (lane == 63) ws[w] = v;
    __syncthreads();
    if (t == 0){
        int a = 0;
        #pragma unroll
        for (int j = 0; j < 4; ++j){ int xv = ws[j]; ws[j] = a; a += xv; }
    }
    __syncthreads();
    int excl = (v - orig) + ws[w] + boff[blockIdx.x];
    if (i < NN){ rowstart[i] = excl; cursor[i] = excl; }
    if (i == NN) rowstart[NN] = ETOT;
}

__global__ void scatter(const int* __restrict__ ei, int* __restrict__ cursor, int* __restrict__ esrc){
    int e = blockIdx.x*256 + threadIdx.x;
    if (e >= ETOT) return;
    int s, d; getsd(ei, e, s, d);
    int pos = atomicAdd(&cursor[d], 1);
    esrc[pos] = s;
}

// ---------------- GEMMs v2: one barrier per tile, weights in VGPRs ----------------

// h1h[N,64](fp16) = x @ W1^T ; a_src1[N,8], a_dst1[N,8](fp32)
// block = 64 nodes, 2 halves of 32; wave computes 8 nodes with acc[8]
__global__ __launch_bounds__(256) void gemm1(const float* __restrict__ x, const float* __restrict__ W1,
        const float* __restrict__ att_s, const float* __restrict__ att_d,
        __half* __restrict__ h1h, float* __restrict__ a_src, float* __restrict__ a_dst){
    __shared__ float w1s[INC*65];    // [k][o] stride 65 -> conflict-free write (65%32==1) & read
    __shared__ float xs[32*132];     // [n][k] stride 132 (16B-aligned rows)
    int tid = threadIdx.x;
    int base = blockIdx.x * 64;
    // stage W1: coalesced global (k fast), conflict-free LDS write
    for (int i = tid; i < INC*F1; i += 256){
        int k = i & 127, o = i >> 7;
        w1s[k*65 + o] = W1[o*INC + k];
    }
    int o = tid & 63, w = tid >> 6;
    float as_w = att_s[o], ad_w = att_d[o];
    int hh = o >> 3, cc = o & 7;
    int nb = w * 8;
    for (int half = 0; half < 2; ++half){
        if (half) __syncthreads();             // protect xs from overwrite
        {   // stage 32 x-rows as float4
            float4* xs4 = (float4*)xs;         // row stride 33 float4
            #pragma unroll
            for (int j = 0; j < 4; ++j){
                int f = tid + 256*j;           // 0..1023
                int row = f >> 5, c4 = f & 31;
                int n = base + half*32 + row;
                float4 v = make_float4(0.f,0.f,0.f,0.f);
                if (n < NN) v = reinterpret_cast<const float4*>(x)[n*32 + c4];
                xs4[row*33 + c4] = v;
            }
        }
        __syncthreads();
        float acc[8];
        #pragma unroll
        for (int n = 0; n < 8; ++n) acc[n] = 0.f;
        #pragma unroll
        for (int kc = 0; kc < 4; ++kc){
            float wk[32];
            #pragma unroll
            for (int j = 0; j < 32; ++j) wk[j] = w1s[(kc*32 + j)*65 + o];
            #pragma unroll
            for (int n = 0; n < 8; n += 2){
                const float* xr0 = &xs[(nb + n)*132 + kc*32];
                const float* xr1 = xr0 + 132;
                #pragma unroll
                for (int j4 = 0; j4 < 8; ++j4){
                    float4 a4 = *(const float4*)(xr0 + j4*4);
                    float4 b4 = *(const float4*)(xr1 + j4*4);
                    acc[n]   = fmaf(a4.x, wk[j4*4+0], acc[n]);
                    acc[n+1] = fmaf(b4.x, wk[j4*4+0], acc[n+1]);
                    acc[n]   = fmaf(a4.y, wk[j4*4+1], acc[n]);
                    acc[n+1] = fmaf(b4.y, wk[j4*4+1], acc[n+1]);
                    acc[n]   = fmaf(a4.z, wk[j4*4+2], acc[n]);
                    acc[n+1] = fmaf(b4.z, wk[j4*4+2], acc[n+1]);
                    acc[n]   = fmaf(a4.w, wk[j4*4+3], acc[n]);
                    acc[n+1] = fmaf(b4.w, wk[j4*4+3], acc[n+1]);
                }
            }
        }
        #pragma unroll
        for (int n = 0; n < 8; ++n){
            int node = base + half*32 + nb + n;
            float v = acc[n];
            float ps = v * as_w, pd = v * ad_w;
            ps += __shfl_xor(ps, 1); ps += __shfl_xor(ps, 2); ps += __shfl_xor(ps, 4);
            pd += __shfl_xor(pd, 1); pd += __shfl_xor(pd, 2); pd += __shfl_xor(pd, 4);
            if (node < NN){
                h1h[node*64 + o] = __float2half(v);
                if (cc == 0){ a_src[node*8 + hh] = ps; a_dst[node*8 + hh] = pd; }
            }
        }
    }
}

// h2h[N,16](fp16) = elu(out1) @ W2^T ; a_src2[N], a_dst2[N]
// block = 128 nodes; wave = 4 slots x 16 ch; slot computes 8 nodes (stride 4)
__global__ __launch_bounds__(256) void gemm2(const float* __restrict__ out1, const float* __restrict__ W2,
        const float* __restrict__ att_s, const float* __restrict__ att_d,
        __half* __restrict__ h2h, float* __restrict__ a_src, float* __restrict__ a_dst){
    __shared__ float w2s[F1*OC];     // [k][o], 4 KB
    __shared__ float xs[128*68];     // [n][k] stride 68
    int tid = threadIdx.x;
    int base = blockIdx.x * 128;
    for (int i = tid; i < F1*OC; i += 256){
        int o = i & 15, k = i >> 4;
        w2s[k*16 + o] = W2[o*F1 + k];
    }
    {   // stage 128 elu(out1) rows as float4
        float4* xs4 = (float4*)xs;   // row stride 17 float4
        #pragma unroll
        for (int j = 0; j < 8; ++j){
            int f = tid + 256*j;     // 0..2047
            int row = f >> 4, c4 = f & 15;
            int n = base + row;
            float4 v = make_float4(0.f,0.f,0.f,0.f);
            if (n < NN) v = reinterpret_cast<const float4*>(out1)[n*16 + c4];
            v.x = v.x > 0.f ? v.x : __expf(v.x) - 1.f;
            v.y = v.y > 0.f ? v.y : __expf(v.y) - 1.f;
            v.z = v.z > 0.f ? v.z : __expf(v.z) - 1.f;
            v.w = v.w > 0.f ? v.w : __expf(v.w) - 1.f;
            xs4[row*17 + c4] = v;
        }
    }
    __syncthreads();
    int lane = tid & 63, w = tid >> 6;
    int o = lane & 15, slot = lane >> 4;
    int nb = w * 32;
    float acc[8];
    #pragma unroll
    for (int n = 0; n < 8; ++n) acc[n] = 0.f;
    #pragma unroll
    for (int kc = 0; kc < 2; ++kc){
        float wk[32];
        #pragma unroll
        for (int j = 0; j < 32; ++j) wk[j] = w2s[(kc*32 + j)*16 + o];
        #pragma unroll
        for (int idx = 0; idx < 8; idx += 2){
            const float* xr0 = &xs[(nb + slot + idx*4)*68 + kc*32];
            const float* xr1 = xr0 + 4*68;
            #pragma unroll
            for (int j4 = 0; j4 < 8; ++j4){
                float4 a4 = *(const float4*)(xr0 + j4*4);
                float4 b4 = *(const float4*)(xr1 + j4*4);
                acc[idx]   = fmaf(a4.x, wk[j4*4+0], acc[idx]);
                acc[idx+1] = fmaf(b4.x, wk[j4*4+0], acc[idx+1]);
                acc[idx]   = fmaf(a4.y, wk[j4*4+1], acc[idx]);
                acc[idx+1] = fmaf(b4.y, wk[j4*4+1], acc[idx+1]);
                acc[idx]   = fmaf(a4.z, wk[j4*4+2], acc[idx]);
                acc[idx+1] = fmaf(b4.z, wk[j4*4+2], acc[idx+1]);
                acc[idx]   = fmaf(a4.w, wk[j4*4+3], acc[idx]);
                acc[idx+1] = fmaf(b4.w, wk[j4*4+3], acc[idx+1]);
            }
        }
    }
    float as_w = att_s[o], ad_w = att_d[o];
    #pragma unroll
    for (int idx = 0; idx < 8; ++idx){
        int node = base + nb + slot + idx*4;
        float v = acc[idx];
        float ps = v * as_w, pd = v * ad_w;
        ps += __shfl_xor(ps, 1); ps += __shfl_xor(ps, 2);
        ps += __shfl_xor(ps, 4); ps += __shfl_xor(ps, 8);
        pd += __shfl_xor(pd, 1); pd += __shfl_xor(pd, 2);
        pd += __shfl_xor(pd, 4); pd += __shfl_xor(pd, 8);
        if (node < NN){
            h2h[node*16 + o] = __float2half(v);
            if (o == 0){ a_src[node] = ps; a_dst[node] = pd; }
        }
    }
}

// ---------------- node-centric aggregation (no-max softmax: e bounded) ----------------

__global__ __launch_bounds__(256) void layer1_node(const int* __restrict__ rowstart,
        const int* __restrict__ esrc, const float* __restrict__ a_src,
        const float* __restrict__ a_dst, const __half* __restrict__ h1h,
        const float* __restrict__ b1, float* __restrict__ out1){
    int wid = (blockIdx.x*256 + threadIdx.x) >> 6;
    int lane = threadIdx.x & 63;
    if (wid >= NN) return;
    int n = wid;
    int h = lane >> 3;
    int r0 = rowstart[n], r1 = rowstart[n+1];
    float ad = a_dst[n*8 + h];
    float den0 = 0.f, acc0 = 0.f, den1 = 0.f, acc1 = 0.f;
    int i = r0;
    for (; i + 1 < r1; i += 2){
        int s0 = esrc[i], s1 = esrc[i+1];
        float e0 = leaky(a_src[s0*8 + h] + ad);
        float e1 = leaky(a_src[s1*8 + h] + ad);
        float hv0 = __half2float(h1h[s0*64 + lane]);
        float hv1 = __half2float(h1h[s1*64 + lane]);
        float p0 = __expf(e0), p1 = __expf(e1);
        den0 += p0; acc0 = fmaf(p0, hv0, acc0);
        den1 += p1; acc1 = fmaf(p1, hv1, acc1);
    }
    if (i < r1){
        int s = esrc[i];
        float p = __expf(leaky(a_src[s*8 + h] + ad));
        den0 += p; acc0 = fmaf(p, __half2float(h1h[s*64 + lane]), acc0);
    }
    float den = den0 + den1, acc = acc0 + acc1;
    out1[n*64 + lane] = acc/(den + 1e-16f) + b1[lane];
}

__global__ __launch_bounds__(256) void layer2_node(const int* __restrict__ rowstart,
        const int* __restrict__ esrc, const float* __restrict__ a_src,
        const float* __restrict__ a_dst, const __half* __restrict__ h2h,
        const float* __restrict__ b2, float* __restrict__ out){
    int wid = (blockIdx.x*256 + threadIdx.x) >> 6;
    int lane = threadIdx.x & 63;
    if (wid >= NN) return;
    int n = wid;
    int slot = lane >> 4, c = lane & 15;
    int r0 = rowstart[n], r1 = rowstart[n+1];
    float ad = a_dst[n];
    float den = 0.f, acc = 0.f;
    for (int i = r0 + slot; i < r1; i += 4){
        int s = esrc[i];
        float p = __expf(leaky(a_src[s] + ad));
        den += p;
        acc = fmaf(p, __half2float(h2h[s*16 + c]), acc);
    }
    den += __shfl_xor(den, 16); den += __shfl_xor(den, 32);
    acc += __shfl_xor(acc, 16); acc += __shfl_xor(acc, 32);
    if (slot == 0) out[n*16 + c] = acc/(den + 1e-16f) + b2[c];
}

extern "C" void kernel_launch(void* const* d_in, const int* in_sizes, int n_in,
                              void* d_out, int out_size, void* d_ws, size_t ws_size,
                              hipStream_t stream){
    const float* x    = (const float*)d_in[0];
    const int*   ei   = (const int*)d_in[1];
    const float* W1   = (const float*)d_in[2];
    const float* as1w = (const float*)d_in[3];
    const float* ad1w = (const float*)d_in[4];
    const float* b1   = (const float*)d_in[5];
    const float* W2   = (const float*)d_in[6];
    const float* as2w = (const float*)d_in[7];
    const float* ad2w = (const float*)d_in[8];
    const float* b2   = (const float*)d_in[9];
    float* out = (float*)d_out;

    float* ws = (float*)d_ws;
    // ws words: h1h 32N | out1 64N | rowstart N+1 | deg N | cursor N | bsum NB | boff NB | esrc ETOT (~23.3 MB)
    __half* h1h     = (__half*)ws;                      // 64N halves = 32N words
    float* out1     = ws + (size_t)32*NN;               // 64N
    int*   rowstart = (int*)(ws + (size_t)96*NN);       // N+1
    int*   deg      = rowstart + NN + 1;                // N
    int*   cursor   = deg + NN;                         // N
    int*   bsum     = cursor + NN;                      // NB
    int*   boff     = bsum + NB;                        // NB
    int*   esrc     = boff + NB;                        // ETOT
    // a_src1/a_dst1 live in d_out (16N floats) until layer1_node; layer2_node overwrites d_out last
    float* a_src1 = out;                                // 8N
    float* a_dst1 = out + (size_t)8*NN;                 // 8N
    __half* h2h   = h1h;                                // 16N halves (h1h dead after layer1_node)
    float* a_src2 = ws + (size_t)8*NN;                  // N
    float* a_dst2 = a_src2 + NN;                        // N

    // CSR build
    hipMemsetAsync(deg, 0, NN*sizeof(int), stream);
    hipLaunchKernelGGL(hist,      dim3((ETOT + 255)/256), dim3(256), 0, stream, ei, deg);
    hipLaunchKernelGGL(block_sum, dim3(NB), dim3(256), 0, stream, deg, bsum);
    hipLaunchKernelGGL(scan_bsum, dim3(1), dim3(256), 0, stream, bsum, boff);
    hipLaunchKernelGGL(scan_final,dim3(NB), dim3(256), 0, stream, deg, boff, rowstart, cursor);
    hipLaunchKernelGGL(scatter,   dim3((ETOT + 255)/256), dim3(256), 0, stream, ei, cursor, esrc);

    // layer 1
    hipLaunchKernelGGL(gemm1, dim3((NN + 63)/64), dim3(256), 0, stream, x, W1, as1w, ad1w, h1h, a_src1, a_dst1);
    hipLaunchKernelGGL(layer1_node, dim3((NN*64 + 255)/256), dim3(256), 0, stream,
                       rowstart, esrc, a_src1, a_dst1, h1h, b1, out1);
    // layer 2
    hipLaunchKernelGGL(gemm2, dim3((NN + 127)/128), dim3(256), 0, stream, out1, W2, as2w, ad2w, h2h, a_src2, a_dst2);
    hipLaunchKernelGGL(layer2_node, dim3((NN*64 + 255)/256), dim3(256), 0, stream,
                       rowstart, esrc, a_src2, a_dst2, h2h, b2, out);
}

// Round 7
// 323.495 us; speedup vs baseline: 2.1834x; 2.1834x over previous
//
#include <hip/hip_runtime.h>
#include <hip/hip_fp16.h>
#include <math.h>

#define NN 50000
#define NE 800000
#define ETOT (NE + NN)
#define INC 128
#define F1 64
#define NH 8
#define OC 16
#define NEG 0.2f
#define NB 196   // ceil(NN/256)

__device__ __forceinline__ float leaky(float x){ return x > 0.f ? x : NEG * x; }

// edge_index arrives as int32 (harness converts integer inputs to int32)
__device__ __forceinline__ void getsd(const int* __restrict__ ei, int e, int& s, int& d){
    if (e < NE){ s = ei[e]; d = ei[NE + e]; }
    else { s = e - NE; d = s; }   // self-loops appended
}

// ---------------- CSR build ----------------

__global__ void hist(const int* __restrict__ ei, int* __restrict__ deg){
    int e = blockIdx.x*256 + threadIdx.x;
    if (e >= ETOT) return;
    int d = (e < NE) ? ei[NE + e] : e - NE;
    atomicAdd(&deg[d], 1);
}

__global__ __launch_bounds__(256) void block_sum(const int* __restrict__ deg, int* __restrict__ bsum){
    int i = blockIdx.x*256 + threadIdx.x;
    int v = (i < NN) ? deg[i] : 0;
    #pragma unroll
    for (int off = 1; off < 64; off <<= 1) v += __shfl_xor(v, off);
    __shared__ int ws[4];
    if ((threadIdx.x & 63) == 0) ws[threadIdx.x >> 6] = v;
    __syncthreads();
    if (threadIdx.x == 0) bsum[blockIdx.x] = ws[0] + ws[1] + ws[2] + ws[3];
}

__global__ __launch_bounds__(256) void scan_bsum(const int* __restrict__ bsum, int* __restrict__ boff){
    __shared__ int s[256];
    int t = threadIdx.x;
    int v = (t < NB) ? bsum[t] : 0;
    s[t] = v; __syncthreads();
    for (int off = 1; off < 256; off <<= 1){
        int u = (t >= off) ? s[t - off] : 0;
        __syncthreads();
        s[t] += u;
        __syncthreads();
    }
    if (t < NB) boff[t] = s[t] - v;   // exclusive
}

__global__ __launch_bounds__(256) void scan_final(const int* __restrict__ deg, const int* __restrict__ boff,
        int* __restrict__ rowstart, int* __restrict__ cursor){
    int t = threadIdx.x, lane = t & 63, w = t >> 6;
    int i = blockIdx.x*256 + t;
    int orig = (i < NN) ? deg[i] : 0;
    int v = orig;
    #pragma unroll
    for (int off = 1; off < 64; off <<= 1){
        int u = __shfl_up(v, off);
        if (lane >= off) v += u;
    }
    __shared__ int ws[4];
    if (lane == 63) ws[w] = v;
    __syncthreads();
    if (t == 0){
        int a = 0;
        #pragma unroll
        for (int j = 0; j < 4; ++j){ int xv = ws[j]; ws[j] = a; a += xv; }
    }
    __syncthreads();
    int excl = (v - orig) + ws[w] + boff[blockIdx.x];
    if (i < NN){ rowstart[i] = excl; cursor[i] = excl; }
    if (i == NN) rowstart[NN] = ETOT;
}

__global__ void scatter(const int* __restrict__ ei, int* __restrict__ cursor, int* __restrict__ esrc){
    int e = blockIdx.x*256 + threadIdx.x;
    if (e >= ETOT) return;
    int s, d; getsd(ei, e, s, d);
    int pos = atomicAdd(&cursor[d], 1);
    esrc[pos] = s;
}

// ---------------- GEMMs v3: bounded registers (wk[16], acc[4]) ----------------

// h1h[N,64](fp16) = x @ W1^T ; a_src1[N,8], a_dst1[N,8](fp32)
// block = 64 nodes, 4 iterations x 16 staged rows; wave computes 4 rows
__global__ __launch_bounds__(256, 4) void gemm1(const float* __restrict__ x, const float* __restrict__ W1,
        const float* __restrict__ att_s, const float* __restrict__ att_d,
        __half* __restrict__ h1h, float* __restrict__ a_src, float* __restrict__ a_dst){
    __shared__ float w1s[INC*65];    // [k][o] stride 65: conflict-free write & read, coalesced global
    __shared__ float xs[16*132];     // 16 rows, stride 132
    int tid = threadIdx.x;
    int base = blockIdx.x * 64;
    for (int i = tid; i < INC*F1; i += 256){
        int k = i & 127, o = i >> 7;
        w1s[k*65 + o] = W1[o*INC + k];   // global coalesced (k fast); LDS bank = (k%32+o)%32 walks
    }
    int o = tid & 63, w = tid >> 6;
    int hh = o >> 3, cc = o & 7;
    float as_w = att_s[o], ad_w = att_d[o];
    for (int it = 0; it < 4; ++it){
        int n0 = base + it*16;
        __syncthreads();
        {   // stage 16 rows: 2 float4 per thread, coalesced
            float4* xs4 = (float4*)xs;   // row stride 33 float4
            int f = tid;
            #pragma unroll
            for (int j = 0; j < 2; ++j){
                int row = f >> 5, c4 = f & 31;
                int n = n0 + row;
                float4 v = make_float4(0.f,0.f,0.f,0.f);
                if (n < NN) v = reinterpret_cast<const float4*>(x)[n*32 + c4];
                xs4[row*33 + c4] = v;
                f += 256;
            }
        }
        __syncthreads();
        float acc0 = 0.f, acc1 = 0.f, acc2 = 0.f, acc3 = 0.f;
        const float* xr = &xs[(w*4)*132];
        for (int kc = 0; kc < 8; ++kc){      // no unroll pragma: keep wk live-range small
            float wk[16];
            #pragma unroll
            for (int j = 0; j < 16; ++j) wk[j] = w1s[(kc*16 + j)*65 + o];
            #pragma unroll
            for (int j4 = 0; j4 < 4; ++j4){
                float4 a = *(const float4*)(xr + 0*132 + kc*16 + j4*4);
                float4 b = *(const float4*)(xr + 1*132 + kc*16 + j4*4);
                float4 c = *(const float4*)(xr + 2*132 + kc*16 + j4*4);
                float4 d = *(const float4*)(xr + 3*132 + kc*16 + j4*4);
                acc0 = fmaf(a.x, wk[j4*4+0], acc0);
                acc1 = fmaf(b.x, wk[j4*4+0], acc1);
                acc2 = fmaf(c.x, wk[j4*4+0], acc2);
                acc3 = fmaf(d.x, wk[j4*4+0], acc3);
                acc0 = fmaf(a.y, wk[j4*4+1], acc0);
                acc1 = fmaf(b.y, wk[j4*4+1], acc1);
                acc2 = fmaf(c.y, wk[j4*4+1], acc2);
                acc3 = fmaf(d.y, wk[j4*4+1], acc3);
                acc0 = fmaf(a.z, wk[j4*4+2], acc0);
                acc1 = fmaf(b.z, wk[j4*4+2], acc1);
                acc2 = fmaf(c.z, wk[j4*4+2], acc2);
                acc3 = fmaf(d.z, wk[j4*4+2], acc3);
                acc0 = fmaf(a.w, wk[j4*4+3], acc0);
                acc1 = fmaf(b.w, wk[j4*4+3], acc1);
                acc2 = fmaf(c.w, wk[j4*4+3], acc2);
                acc3 = fmaf(d.w, wk[j4*4+3], acc3);
            }
        }
        #pragma unroll
        for (int r = 0; r < 4; ++r){
            float v = (r == 0) ? acc0 : (r == 1) ? acc1 : (r == 2) ? acc2 : acc3;
            int node = n0 + w*4 + r;
            float ps = v * as_w, pd = v * ad_w;
            ps += __shfl_xor(ps, 1); ps += __shfl_xor(ps, 2); ps += __shfl_xor(ps, 4);
            pd += __shfl_xor(pd, 1); pd += __shfl_xor(pd, 2); pd += __shfl_xor(pd, 4);
            if (node < NN){
                h1h[node*64 + o] = __float2half(v);
                if (cc == 0){ a_src[node*8 + hh] = ps; a_dst[node*8 + hh] = pd; }
            }
        }
    }
}

// h2h[N,16](fp16) = elu(out1) @ W2^T ; a_src2[N], a_dst2[N]
// block = 64 nodes staged once; wave = 4 slots x 16 ch; slot computes 4 rows
__global__ __launch_bounds__(256, 4) void gemm2(const float* __restrict__ out1, const float* __restrict__ W2,
        const float* __restrict__ att_s, const float* __restrict__ att_d,
        __half* __restrict__ h2h, float* __restrict__ a_src, float* __restrict__ a_dst){
    __shared__ float w2s[F1*OC];     // [k][o], 4 KB
    __shared__ float xs[64*68];      // [n][k] stride 68, 17.4 KB
    int tid = threadIdx.x;
    int base = blockIdx.x * 64;
    for (int i = tid; i < F1*OC; i += 256){
        int o = i & 15, k = i >> 4;
        w2s[k*16 + o] = W2[o*F1 + k];
    }
    {   // stage 64 elu(out1) rows: 4 float4 per thread, coalesced
        float4* xs4 = (float4*)xs;   // row stride 17 float4
        int f = tid;
        #pragma unroll
        for (int j = 0; j < 4; ++j){
            int row = f >> 4, c4 = f & 15;
            int n = base + row;
            float4 v = make_float4(0.f,0.f,0.f,0.f);
            if (n < NN) v = reinterpret_cast<const float4*>(out1)[n*16 + c4];
            v.x = v.x > 0.f ? v.x : __expf(v.x) - 1.f;
            v.y = v.y > 0.f ? v.y : __expf(v.y) - 1.f;
            v.z = v.z > 0.f ? v.z : __expf(v.z) - 1.f;
            v.w = v.w > 0.f ? v.w : __expf(v.w) - 1.f;
            xs4[row*17 + c4] = v;
            f += 256;
        }
    }
    __syncthreads();
    int lane = tid & 63, w = tid >> 6;
    int o = lane & 15, slot = lane >> 4;
    float as_w = att_s[o], ad_w = att_d[o];
    float acc0 = 0.f, acc1 = 0.f, acc2 = 0.f, acc3 = 0.f;
    const float* xr = &xs[(w*16 + slot)*68];     // slot's rows: +0, +4*68, +8*68, +12*68
    for (int kc = 0; kc < 4; ++kc){
        float wk[16];
        #pragma unroll
        for (int j = 0; j < 16; ++j) wk[j] = w2s[(kc*16 + j)*16 + o];
        #pragma unroll
        for (int j4 = 0; j4 < 4; ++j4){
            float4 a = *(const float4*)(xr + 0*272 + kc*16 + j4*4);
            float4 b = *(const float4*)(xr + 1*272 + kc*16 + j4*4);
            float4 c = *(const float4*)(xr + 2*272 + kc*16 + j4*4);
            float4 d = *(const float4*)(xr + 3*272 + kc*16 + j4*4);
            acc0 = fmaf(a.x, wk[j4*4+0], acc0);
            acc1 = fmaf(b.x, wk[j4*4+0], acc1);
            acc2 = fmaf(c.x, wk[j4*4+0], acc2);
            acc3 = fmaf(d.x, wk[j4*4+0], acc3);
            acc0 = fmaf(a.y, wk[j4*4+1], acc0);
            acc1 = fmaf(b.y, wk[j4*4+1], acc1);
            acc2 = fmaf(c.y, wk[j4*4+1], acc2);
            acc3 = fmaf(d.y, wk[j4*4+1], acc3);
            acc0 = fmaf(a.z, wk[j4*4+2], acc0);
            acc1 = fmaf(b.z, wk[j4*4+2], acc1);
            acc2 = fmaf(c.z, wk[j4*4+2], acc2);
            acc3 = fmaf(d.z, wk[j4*4+2], acc3);
            acc0 = fmaf(a.w, wk[j4*4+3], acc0);
            acc1 = fmaf(b.w, wk[j4*4+3], acc1);
            acc2 = fmaf(c.w, wk[j4*4+3], acc2);
            acc3 = fmaf(d.w, wk[j4*4+3], acc3);
        }
    }
    #pragma unroll
    for (int r = 0; r < 4; ++r){
        float v = (r == 0) ? acc0 : (r == 1) ? acc1 : (r == 2) ? acc2 : acc3;
        int node = base + w*16 + slot + r*4;
        float ps = v * as_w, pd = v * ad_w;
        ps += __shfl_xor(ps, 1); ps += __shfl_xor(ps, 2);
        ps += __shfl_xor(ps, 4); ps += __shfl_xor(ps, 8);
        pd += __shfl_xor(pd, 1); pd += __shfl_xor(pd, 2);
        pd += __shfl_xor(pd, 4); pd += __shfl_xor(pd, 8);
        if (node < NN){
            h2h[node*16 + o] = __float2half(v);
            if (o == 0){ a_src[node] = ps; a_dst[node] = pd; }
        }
    }
}

// ---------------- node-centric aggregation (no-max softmax: e bounded) ----------------

__global__ __launch_bounds__(256) void layer1_node(const int* __restrict__ rowstart,
        const int* __restrict__ esrc, const float* __restrict__ a_src,
        const float* __restrict__ a_dst, const __half* __restrict__ h1h,
        const float* __restrict__ b1, float* __restrict__ out1){
    int wid = (blockIdx.x*256 + threadIdx.x) >> 6;
    int lane = threadIdx.x & 63;
    if (wid >= NN) return;
    int n = wid;
    int h = lane >> 3;
    int r0 = rowstart[n], r1 = rowstart[n+1];
    float ad = a_dst[n*8 + h];
    float den0 = 0.f, acc0 = 0.f, den1 = 0.f, acc1 = 0.f;
    int i = r0;
    for (; i + 1 < r1; i += 2){
        int s0 = esrc[i], s1 = esrc[i+1];
        float e0 = leaky(a_src[s0*8 + h] + ad);
        float e1 = leaky(a_src[s1*8 + h] + ad);
        float hv0 = __half2float(h1h[s0*64 + lane]);
        float hv1 = __half2float(h1h[s1*64 + lane]);
        float p0 = __expf(e0), p1 = __expf(e1);
        den0 += p0; acc0 = fmaf(p0, hv0, acc0);
        den1 += p1; acc1 = fmaf(p1, hv1, acc1);
    }
    if (i < r1){
        int s = esrc[i];
        float p = __expf(leaky(a_src[s*8 + h] + ad));
        den0 += p; acc0 = fmaf(p, __half2float(h1h[s*64 + lane]), acc0);
    }
    float den = den0 + den1, acc = acc0 + acc1;
    out1[n*64 + lane] = acc/(den + 1e-16f) + b1[lane];
}

__global__ __launch_bounds__(256) void layer2_node(const int* __restrict__ rowstart,
        const int* __restrict__ esrc, const float* __restrict__ a_src,
        const float* __restrict__ a_dst, const __half* __restrict__ h2h,
        const float* __restrict__ b2, float* __restrict__ out){
    int wid = (blockIdx.x*256 + threadIdx.x) >> 6;
    int lane = threadIdx.x & 63;
    if (wid >= NN) return;
    int n = wid;
    int slot = lane >> 4, c = lane & 15;
    int r0 = rowstart[n], r1 = rowstart[n+1];
    float ad = a_dst[n];
    float den = 0.f, acc = 0.f;
    for (int i = r0 + slot; i < r1; i += 4){
        int s = esrc[i];
        float p = __expf(leaky(a_src[s] + ad));
        den += p;
        acc = fmaf(p, __half2float(h2h[s*16 + c]), acc);
    }
    den += __shfl_xor(den, 16); den += __shfl_xor(den, 32);
    acc += __shfl_xor(acc, 16); acc += __shfl_xor(acc, 32);
    if (slot == 0) out[n*16 + c] = acc/(den + 1e-16f) + b2[c];
}

extern "C" void kernel_launch(void* const* d_in, const int* in_sizes, int n_in,
                              void* d_out, int out_size, void* d_ws, size_t ws_size,
                              hipStream_t stream){
    const float* x    = (const float*)d_in[0];
    const int*   ei   = (const int*)d_in[1];
    const float* W1   = (const float*)d_in[2];
    const float* as1w = (const float*)d_in[3];
    const float* ad1w = (const float*)d_in[4];
    const float* b1   = (const float*)d_in[5];
    const float* W2   = (const float*)d_in[6];
    const float* as2w = (const float*)d_in[7];
    const float* ad2w = (const float*)d_in[8];
    const float* b2   = (const float*)d_in[9];
    float* out = (float*)d_out;

    float* ws = (float*)d_ws;
    // ws words: h1h 32N | out1 64N | rowstart N+1 | deg N | cursor N | bsum NB | boff NB | esrc ETOT (~23.3 MB)
    __half* h1h     = (__half*)ws;                      // 64N halves = 32N words
    float* out1     = ws + (size_t)32*NN;               // 64N
    int*   rowstart = (int*)(ws + (size_t)96*NN);       // N+1
    int*   deg      = rowstart + NN + 1;                // N
    int*   cursor   = deg + NN;                         // N
    int*   bsum     = cursor + NN;                      // NB
    int*   boff     = bsum + NB;                        // NB
    int*   esrc     = boff + NB;                        // ETOT
    // a_src1/a_dst1 live in d_out (16N floats) until layer1_node; layer2_node overwrites d_out last
    float* a_src1 = out;                                // 8N
    float* a_dst1 = out + (size_t)8*NN;                 // 8N
    __half* h2h   = h1h;                                // 16N halves (h1h dead after layer1_node)
    float* a_src2 = ws + (size_t)8*NN;                  // N
    float* a_dst2 = a_src2 + NN;                        // N

    // CSR build
    hipMemsetAsync(deg, 0, NN*sizeof(int), stream);
    hipLaunchKernelGGL(hist,      dim3((ETOT + 255)/256), dim3(256), 0, stream, ei, deg);
    hipLaunchKernelGGL(block_sum, dim3(NB), dim3(256), 0, stream, deg, bsum);
    hipLaunchKernelGGL(scan_bsum, dim3(1), dim3(256), 0, stream, bsum, boff);
    hipLaunchKernelGGL(scan_final,dim3(NB), dim3(256), 0, stream, deg, boff, rowstart, cursor);
    hipLaunchKernelGGL(scatter,   dim3((ETOT + 255)/256), dim3(256), 0, stream, ei, cursor, esrc);

    // layer 1
    hipLaunchKernelGGL(gemm1, dim3((NN + 63)/64), dim3(256), 0, stream, x, W1, as1w, ad1w, h1h, a_src1, a_dst1);
    hipLaunchKernelGGL(layer1_node, dim3((NN*64 + 255)/256), dim3(256), 0, stream,
                       rowstart, esrc, a_src1, a_dst1, h1h, b1, out1);
    // layer 2
    hipLaunchKernelGGL(gemm2, dim3((NN + 63)/64), dim3(256), 0, stream, out1, W2, as2w, ad2w, h2h, a_src2, a_dst2);
    hipLaunchKernelGGL(layer2_node, dim3((NN*64 + 255)/256), dim3(256), 0, stream,
                       rowstart, esrc, a_src2, a_dst2, h2h, b2, out);
}

// Round 8
// 232.660 us; speedup vs baseline: 3.0359x; 1.3904x over previous
//
#include <hip/hip_runtime.h>
#include <hip/hip_fp16.h>
#include <math.h>

#define NN 50000
#define NE 800000
#define ETOT (NE + NN)
#define INC 128
#define F1 64
#define NH 8
#define OC 16
#define NEG 0.2f
#define NB 196   // ceil(NN/256)

__device__ __forceinline__ float leaky(float x){ return x > 0.f ? x : NEG * x; }

__device__ __forceinline__ void getsd(const int* __restrict__ ei, int e, int& s, int& d){
    if (e < NE){ s = ei[e]; d = ei[NE + e]; }
    else { s = e - NE; d = s; }   // self-loops appended
}

// ---------------- CSR build ----------------

__global__ void hist(const int* __restrict__ ei, int* __restrict__ deg){
    int e = blockIdx.x*256 + threadIdx.x;
    if (e >= ETOT) return;
    int d = (e < NE) ? ei[NE + e] : e - NE;
    atomicAdd(&deg[d], 1);
}

__global__ __launch_bounds__(256) void block_sum(const int* __restrict__ deg, int* __restrict__ bsum){
    int i = blockIdx.x*256 + threadIdx.x;
    int v = (i < NN) ? deg[i] : 0;
    #pragma unroll
    for (int off = 1; off < 64; off <<= 1) v += __shfl_xor(v, off);
    __shared__ int ws[4];
    if ((threadIdx.x & 63) == 0) ws[threadIdx.x >> 6] = v;
    __syncthreads();
    if (threadIdx.x == 0) bsum[blockIdx.x] = ws[0] + ws[1] + ws[2] + ws[3];
}

__global__ __launch_bounds__(256) void scan_bsum(const int* __restrict__ bsum, int* __restrict__ boff){
    __shared__ int s[256];
    int t = threadIdx.x;
    int v = (t < NB) ? bsum[t] : 0;
    s[t] = v; __syncthreads();
    for (int off = 1; off < 256; off <<= 1){
        int u = (t >= off) ? s[t - off] : 0;
        __syncthreads();
        s[t] += u;
        __syncthreads();
    }
    if (t < NB) boff[t] = s[t] - v;   // exclusive
}

__global__ __launch_bounds__(256) void scan_final(const int* __restrict__ deg, const int* __restrict__ boff,
        int* __restrict__ rowstart, int* __restrict__ cursor){
    int t = threadIdx.x, lane = t & 63, w = t >> 6;
    int i = blockIdx.x*256 + t;
    int orig = (i < NN) ? deg[i] : 0;
    int v = orig;
    #pragma unroll
    for (int off = 1; off < 64; off <<= 1){
        int u = __shfl_up(v, off);
        if (lane >= off) v += u;
    }
    __shared__ int ws[4];
    if (lane == 63) ws[w] = v;
    __syncthreads();
    if (t == 0){
        int a = 0;
        #pragma unroll
        for (int j = 0; j < 4; ++j){ int xv = ws[j]; ws[j] = a; a += xv; }
    }
    __syncthreads();
    int excl = (v - orig) + ws[w] + boff[blockIdx.x];
    if (i < NN){ rowstart[i] = excl; cursor[i] = excl; }
    if (i == NN) rowstart[NN] = ETOT;
}

__global__ void scatter(const int* __restrict__ ei, int* __restrict__ cursor, int* __restrict__ esrc){
    int e = blockIdx.x*256 + threadIdx.x;
    if (e >= ETOT) return;
    int s, d; getsd(ei, e, s, d);
    int pos = atomicAdd(&cursor[d], 1);
    esrc[pos] = s;
}

// ---------------- GEMM v4: k-sliced waves, W in named registers ----------------

// h1h[N,64](fp16) = x @ W1^T.  lane=(oL,ks): outputs o1,o2; k-slice ks*32..+32.
// Waves 0,1: rows 0..31 (outputs 0..31 / 32..63); waves 2,3: rows 32..63.
__global__ __launch_bounds__(256, 4) void gemm1(const float* __restrict__ x, const float* __restrict__ W1,
        __half* __restrict__ h1h){
    __shared__ float xs[64*144];   // [row][slice ks][36]: ks*36 -> distinct banks, 16B aligned
    int tid = threadIdx.x;
    int base = blockIdx.x * 64;
    int w = tid >> 6, lane = tid & 63;
    int oL = lane >> 2, ks = lane & 3;
    int o1 = (w & 1)*32 + oL, o2 = o1 + 16;
    // W fragments: loaded ONCE, constant-indexed -> registers
    float4 wra[8], wrb[8];
    {
        const float4* W4 = reinterpret_cast<const float4*>(W1);
        #pragma unroll
        for (int j4 = 0; j4 < 8; ++j4){
            wra[j4] = W4[o1*32 + ks*8 + j4];
            wrb[j4] = W4[o2*32 + ks*8 + j4];
        }
    }
    {   // stage 64 x-rows: 8 float4 per thread, coalesced global
        #pragma unroll
        for (int j = 0; j < 8; ++j){
            int f = tid + 256*j;              // 0..2047
            int row = f >> 5, c4 = f & 31;
            int n = base + row;
            float4 v = make_float4(0.f,0.f,0.f,0.f);
            if (n < NN) v = reinterpret_cast<const float4*>(x)[n*32 + c4];
            int sk = c4 >> 3, j4 = c4 & 7;
            *(float4*)(&xs[row*144 + sk*36 + j4*4]) = v;
        }
    }
    __syncthreads();
    int rbase = (w >> 1) * 32;
    for (int r = 0; r < 32; ++r){
        int row = rbase + r;
        const float* xb = &xs[row*144 + ks*36];
        float acc1 = 0.f, acc2 = 0.f;
        #pragma unroll
        for (int j4 = 0; j4 < 8; ++j4){
            float4 xv = *(const float4*)(xb + j4*4);
            acc1 = fmaf(xv.x, wra[j4].x, acc1);
            acc2 = fmaf(xv.x, wrb[j4].x, acc2);
            acc1 = fmaf(xv.y, wra[j4].y, acc1);
            acc2 = fmaf(xv.y, wrb[j4].y, acc2);
            acc1 = fmaf(xv.z, wra[j4].z, acc1);
            acc2 = fmaf(xv.z, wrb[j4].z, acc2);
            acc1 = fmaf(xv.w, wra[j4].w, acc1);
            acc2 = fmaf(xv.w, wrb[j4].w, acc2);
        }
        acc1 += __shfl_xor(acc1, 1); acc1 += __shfl_xor(acc1, 2);
        acc2 += __shfl_xor(acc2, 1); acc2 += __shfl_xor(acc2, 2);
        int node = base + row;
        if (ks == 0 && node < NN){
            h1h[node*64 + o1] = __float2half(acc1);
            h1h[node*64 + o2] = __float2half(acc2);
        }
    }
}

// h2h[N,16](fp16) = elu(out1) @ W2^T.  lane=(o,ks): 1 output, k-slice ks*16..+16.
// wave w handles rows w*16..+15.
__global__ __launch_bounds__(256, 4) void gemm2(const float* __restrict__ out1, const float* __restrict__ W2,
        __half* __restrict__ h2h){
    __shared__ float xs[64*80];    // [row][slice ks][20]
    int tid = threadIdx.x;
    int base = blockIdx.x * 64;
    int w = tid >> 6, lane = tid & 63;
    int o = lane >> 2, ks = lane & 3;
    float4 wr[4];
    {
        const float4* W4 = reinterpret_cast<const float4*>(W2);
        #pragma unroll
        for (int j4 = 0; j4 < 4; ++j4)
            wr[j4] = W4[o*16 + ks*4 + j4];
    }
    {   // stage 64 elu(out1) rows: 4 float4 per thread
        #pragma unroll
        for (int j = 0; j < 4; ++j){
            int f = tid + 256*j;              // 0..1023
            int row = f >> 4, c4 = f & 15;
            int n = base + row;
            float4 v = make_float4(0.f,0.f,0.f,0.f);
            if (n < NN) v = reinterpret_cast<const float4*>(out1)[n*16 + c4];
            v.x = v.x > 0.f ? v.x : __expf(v.x) - 1.f;
            v.y = v.y > 0.f ? v.y : __expf(v.y) - 1.f;
            v.z = v.z > 0.f ? v.z : __expf(v.z) - 1.f;
            v.w = v.w > 0.f ? v.w : __expf(v.w) - 1.f;
            int sk = c4 >> 2, j4 = c4 & 3;
            *(float4*)(&xs[row*80 + sk*20 + j4*4]) = v;
        }
    }
    __syncthreads();
    for (int r = 0; r < 16; ++r){
        int row = w*16 + r;
        const float* xb = &xs[row*80 + ks*20];
        float acc = 0.f;
        #pragma unroll
        for (int j4 = 0; j4 < 4; ++j4){
            float4 xv = *(const float4*)(xb + j4*4);
            acc = fmaf(xv.x, wr[j4].x, acc);
            acc = fmaf(xv.y, wr[j4].y, acc);
            acc = fmaf(xv.z, wr[j4].z, acc);
            acc = fmaf(xv.w, wr[j4].w, acc);
        }
        acc += __shfl_xor(acc, 1); acc += __shfl_xor(acc, 2);
        int node = base + row;
        if (ks == 0 && node < NN)
            h2h[node*16 + o] = __float2half(acc);
    }
}

// ---------------- attention logits from fp16 h ----------------

// thread = (n,h): a_src1[n,8], a_dst1[n,8]
__global__ __launch_bounds__(256) void att1(const __half* __restrict__ h1h,
        const float* __restrict__ att_s, const float* __restrict__ att_d,
        float* __restrict__ a_src, float* __restrict__ a_dst){
    int idx = blockIdx.x*256 + threadIdx.x;
    if (idx >= NN*NH) return;
    int n = idx >> 3, h = idx & 7;
    float4 raw = reinterpret_cast<const float4*>(h1h)[n*8 + h];
    const __half2* hp = (const __half2*)&raw;
    float ds_ = 0.f, dd_ = 0.f;
    #pragma unroll
    for (int q = 0; q < 4; ++q){
        float2 f = __half22float2(hp[q]);
        ds_ = fmaf(f.x, att_s[h*8 + 2*q],     ds_);
        ds_ = fmaf(f.y, att_s[h*8 + 2*q + 1], ds_);
        dd_ = fmaf(f.x, att_d[h*8 + 2*q],     dd_);
        dd_ = fmaf(f.y, att_d[h*8 + 2*q + 1], dd_);
    }
    a_src[idx] = ds_;
    a_dst[idx] = dd_;
}

// thread = n: a_src2[n], a_dst2[n]
__global__ __launch_bounds__(256) void att2(const __half* __restrict__ h2h,
        const float* __restrict__ att_s, const float* __restrict__ att_d,
        float* __restrict__ a_src, float* __restrict__ a_dst){
    int n = blockIdx.x*256 + threadIdx.x;
    if (n >= NN) return;
    float4 r0 = reinterpret_cast<const float4*>(h2h)[n*2];
    float4 r1 = reinterpret_cast<const float4*>(h2h)[n*2 + 1];
    const __half2* hp0 = (const __half2*)&r0;
    const __half2* hp1 = (const __half2*)&r1;
    float ds_ = 0.f, dd_ = 0.f;
    #pragma unroll
    for (int q = 0; q < 4; ++q){
        float2 f = __half22float2(hp0[q]);
        ds_ = fmaf(f.x, att_s[2*q],   ds_); ds_ = fmaf(f.y, att_s[2*q+1], ds_);
        dd_ = fmaf(f.x, att_d[2*q],   dd_); dd_ = fmaf(f.y, att_d[2*q+1], dd_);
    }
    #pragma unroll
    for (int q = 0; q < 4; ++q){
        float2 f = __half22float2(hp1[q]);
        ds_ = fmaf(f.x, att_s[8+2*q], ds_); ds_ = fmaf(f.y, att_s[8+2*q+1], ds_);
        dd_ = fmaf(f.x, att_d[8+2*q], dd_); dd_ = fmaf(f.y, att_d[8+2*q+1], dd_);
    }
    a_src[n] = ds_;
    a_dst[n] = dd_;
}

// ---------------- node-centric aggregation (no-max softmax: e bounded) ----------------

__global__ __launch_bounds__(256) void layer1_node(const int* __restrict__ rowstart,
        const int* __restrict__ esrc, const float* __restrict__ a_src,
        const float* __restrict__ a_dst, const __half* __restrict__ h1h,
        const float* __restrict__ b1, float* __restrict__ out1){
    int wid = (blockIdx.x*256 + threadIdx.x) >> 6;
    int lane = threadIdx.x & 63;
    if (wid >= NN) return;
    int n = wid;
    int h = lane >> 3;
    int r0 = rowstart[n], r1 = rowstart[n+1];
    float ad = a_dst[n*8 + h];
    float den0 = 0.f, acc0 = 0.f, den1 = 0.f, acc1 = 0.f;
    int i = r0;
    for (; i + 1 < r1; i += 2){
        int s0 = esrc[i], s1 = esrc[i+1];
        float e0 = leaky(a_src[s0*8 + h] + ad);
        float e1 = leaky(a_src[s1*8 + h] + ad);
        float hv0 = __half2float(h1h[s0*64 + lane]);
        float hv1 = __half2float(h1h[s1*64 + lane]);
        float p0 = __expf(e0), p1 = __expf(e1);
        den0 += p0; acc0 = fmaf(p0, hv0, acc0);
        den1 += p1; acc1 = fmaf(p1, hv1, acc1);
    }
    if (i < r1){
        int s = esrc[i];
        float p = __expf(leaky(a_src[s*8 + h] + ad));
        den0 += p; acc0 = fmaf(p, __half2float(h1h[s*64 + lane]), acc0);
    }
    float den = den0 + den1, acc = acc0 + acc1;
    out1[n*64 + lane] = acc/(den + 1e-16f) + b1[lane];
}

__global__ __launch_bounds__(256) void layer2_node(const int* __restrict__ rowstart,
        const int* __restrict__ esrc, const float* __restrict__ a_src,
        const float* __restrict__ a_dst, const __half* __restrict__ h2h,
        const float* __restrict__ b2, float* __restrict__ out){
    int wid = (blockIdx.x*256 + threadIdx.x) >> 6;
    int lane = threadIdx.x & 63;
    if (wid >= NN) return;
    int n = wid;
    int slot = lane >> 4, c = lane & 15;
    int r0 = rowstart[n], r1 = rowstart[n+1];
    float ad = a_dst[n];
    float den = 0.f, acc = 0.f;
    for (int i = r0 + slot; i < r1; i += 4){
        int s = esrc[i];
        float p = __expf(leaky(a_src[s] + ad));
        den += p;
        acc = fmaf(p, __half2float(h2h[s*16 + c]), acc);
    }
    den += __shfl_xor(den, 16); den += __shfl_xor(den, 32);
    acc += __shfl_xor(acc, 16); acc += __shfl_xor(acc, 32);
    if (slot == 0) out[n*16 + c] = acc/(den + 1e-16f) + b2[c];
}

extern "C" void kernel_launch(void* const* d_in, const int* in_sizes, int n_in,
                              void* d_out, int out_size, void* d_ws, size_t ws_size,
                              hipStream_t stream){
    const float* x    = (const float*)d_in[0];
    const int*   ei   = (const int*)d_in[1];
    const float* W1   = (const float*)d_in[2];
    const float* as1w = (const float*)d_in[3];
    const float* ad1w = (const float*)d_in[4];
    const float* b1   = (const float*)d_in[5];
    const float* W2   = (const float*)d_in[6];
    const float* as2w = (const float*)d_in[7];
    const float* ad2w = (const float*)d_in[8];
    const float* b2   = (const float*)d_in[9];
    float* out = (float*)d_out;

    float* ws = (float*)d_ws;
    // ws words: h1h 32N | out1 64N | rowstart N+1 | deg N | cursor N | bsum NB | boff NB | esrc ETOT (~23.3 MB)
    __half* h1h     = (__half*)ws;                      // 64N halves = 32N words
    float* out1     = ws + (size_t)32*NN;               // 64N
    int*   rowstart = (int*)(ws + (size_t)96*NN);       // N+1
    int*   deg      = rowstart + NN + 1;                // N
    int*   cursor   = deg + NN;                         // N
    int*   bsum     = cursor + NN;                      // NB
    int*   boff     = bsum + NB;                        // NB
    int*   esrc     = boff + NB;                        // ETOT
    // a_src1/a_dst1 live in d_out (16N floats) until layer1_node; layer2_node overwrites d_out last
    float* a_src1 = out;                                // 8N
    float* a_dst1 = out + (size_t)8*NN;                 // 8N
    __half* h2h   = h1h;                                // 16N halves (h1h dead after layer1_node)
    float* a_src2 = ws + (size_t)8*NN;                  // N  (after h2h's 8N words)
    float* a_dst2 = a_src2 + NN;                        // N

    // CSR build
    hipMemsetAsync(deg, 0, NN*sizeof(int), stream);
    hipLaunchKernelGGL(hist,      dim3((ETOT + 255)/256), dim3(256), 0, stream, ei, deg);
    hipLaunchKernelGGL(block_sum, dim3(NB), dim3(256), 0, stream, deg, bsum);
    hipLaunchKernelGGL(scan_bsum, dim3(1), dim3(256), 0, stream, bsum, boff);
    hipLaunchKernelGGL(scan_final,dim3(NB), dim3(256), 0, stream, deg, boff, rowstart, cursor);
    hipLaunchKernelGGL(scatter,   dim3((ETOT + 255)/256), dim3(256), 0, stream, ei, cursor, esrc);

    // layer 1
    hipLaunchKernelGGL(gemm1, dim3((NN + 63)/64), dim3(256), 0, stream, x, W1, h1h);
    hipLaunchKernelGGL(att1,  dim3((NN*NH + 255)/256), dim3(256), 0, stream, h1h, as1w, ad1w, a_src1, a_dst1);
    hipLaunchKernelGGL(layer1_node, dim3((NN*64 + 255)/256), dim3(256), 0, stream,
                       rowstart, esrc, a_src1, a_dst1, h1h, b1, out1);
    // layer 2
    hipLaunchKernelGGL(gemm2, dim3((NN + 63)/64), dim3(256), 0, stream, out1, W2, h2h);
    hipLaunchKernelGGL(att2,  dim3((NN + 255)/256), dim3(256), 0, stream, h2h, as2w, ad2w, a_src2, a_dst2);
    hipLaunchKernelGGL(layer2_node, dim3((NN*64 + 255)/256), dim3(256), 0, stream,
                       rowstart, esrc, a_src2, a_dst2, h2h, b2, out);
}

// Round 9
// 176.938 us; speedup vs baseline: 3.9920x; 1.3149x over previous
//
#include <hip/hip_runtime.h>
#include <hip/hip_fp16.h>
#include <math.h>

#define NN 50000
#define NE 800000
#define ETOT (NE + NN)
#define INC 128
#define F1 64
#define NH 8
#define OC 16
#define NEG 0.2f
#define NB 196        // ceil(NN/256) for node scan
#define BSH 7         // 128 dsts per bucket
#define NBUK 391      // ceil(NN/128)
#define CHUNK_A 4096
#define NBLK_A ((ETOT + CHUNK_A - 1) / CHUNK_A)   // 208

__device__ __forceinline__ float leaky(float x){ return x > 0.f ? x : NEG * x; }

__device__ __forceinline__ void getsd(const int* __restrict__ ei, int e, int& s, int& d){
    if (e < NE){ s = ei[e]; d = ei[NE + e]; }
    else { s = e - NE; d = s; }   // self-loops appended
}

// ---------------- CSR build: two-level binning (no random global atomics) ----------------

__global__ __launch_bounds__(256) void bucket_hist(const int* __restrict__ ei, int* __restrict__ gbcnt){
    __shared__ int bcnt[NBUK];
    int tid = threadIdx.x;
    for (int j = tid; j < NBUK; j += 256) bcnt[j] = 0;
    __syncthreads();
    int e0 = blockIdx.x * CHUNK_A;
    int e1 = e0 + CHUNK_A; if (e1 > ETOT) e1 = ETOT;
    for (int e = e0 + tid; e < e1; e += 256){
        int d = (e < NE) ? ei[NE + e] : e - NE;
        atomicAdd(&bcnt[d >> BSH], 1);
    }
    __syncthreads();
    for (int j = tid; j < NBUK; j += 256)
        if (bcnt[j]) atomicAdd(&gbcnt[j], bcnt[j]);
}

__global__ __launch_bounds__(512) void bucket_scan(const int* __restrict__ gbcnt,
        int* __restrict__ gboff, int* __restrict__ gbcur){
    __shared__ int s[512];
    int t = threadIdx.x;
    int v = (t < NBUK) ? gbcnt[t] : 0;
    s[t] = v; __syncthreads();
    for (int off = 1; off < 512; off <<= 1){
        int u = (t >= off) ? s[t - off] : 0;
        __syncthreads();
        s[t] += u;
        __syncthreads();
    }
    if (t < NBUK){ int ex = s[t] - v; gboff[t] = ex; gbcur[t] = ex; }
    if (t == 0) gboff[NBUK] = ETOT;
}

__global__ __launch_bounds__(256) void bucket_scatter(const int* __restrict__ ei,
        int* __restrict__ gbcur, unsigned* __restrict__ packed){
    __shared__ int bcnt[NBUK];
    int tid = threadIdx.x;
    for (int j = tid; j < NBUK; j += 256) bcnt[j] = 0;
    __syncthreads();
    int e0 = blockIdx.x * CHUNK_A;
    int e1 = e0 + CHUNK_A; if (e1 > ETOT) e1 = ETOT;
    for (int e = e0 + tid; e < e1; e += 256){
        int d = (e < NE) ? ei[NE + e] : e - NE;
        atomicAdd(&bcnt[d >> BSH], 1);
    }
    __syncthreads();
    for (int j = tid; j < NBUK; j += 256){
        int c = bcnt[j];
        bcnt[j] = c ? atomicAdd(&gbcur[j], c) : 0;   // bcnt becomes block-local cursor base
    }
    __syncthreads();
    for (int e = e0 + tid; e < e1; e += 256){
        int s, d; getsd(ei, e, s, d);
        int pos = atomicAdd(&bcnt[d >> BSH], 1);
        packed[pos] = ((unsigned)s << 16) | (unsigned)d;   // s,d < 65536
    }
}

// one block per bucket: deg via LDS atomics only
__global__ __launch_bounds__(256) void deg_count(const unsigned* __restrict__ packed,
        const int* __restrict__ gboff, int* __restrict__ deg){
    __shared__ int ldeg[1 << BSH];
    int b = blockIdx.x, tid = threadIdx.x;
    if (tid < (1 << BSH)) ldeg[tid] = 0;
    __syncthreads();
    int p0 = gboff[b], p1 = gboff[b+1];
    for (int i = p0 + tid; i < p1; i += 256)
        atomicAdd(&ldeg[packed[i] & ((1 << BSH) - 1)], 1);
    __syncthreads();
    int n0 = b << BSH;
    if (tid < (1 << BSH) && n0 + tid < NN) deg[n0 + tid] = ldeg[tid];
}

__global__ __launch_bounds__(256) void block_sum(const int* __restrict__ deg, int* __restrict__ bsum){
    int i = blockIdx.x*256 + threadIdx.x;
    int v = (i < NN) ? deg[i] : 0;
    #pragma unroll
    for (int off = 1; off < 64; off <<= 1) v += __shfl_xor(v, off);
    __shared__ int ws[4];
    if ((threadIdx.x & 63) == 0) ws[threadIdx.x >> 6] = v;
    __syncthreads();
    if (threadIdx.x == 0) bsum[blockIdx.x] = ws[0] + ws[1] + ws[2] + ws[3];
}

__global__ __launch_bounds__(256) void scan_bsum(const int* __restrict__ bsum, int* __restrict__ boff){
    __shared__ int s[256];
    int t = threadIdx.x;
    int v = (t < NB) ? bsum[t] : 0;
    s[t] = v; __syncthreads();
    for (int off = 1; off < 256; off <<= 1){
        int u = (t >= off) ? s[t - off] : 0;
        __syncthreads();
        s[t] += u;
        __syncthreads();
    }
    if (t < NB) boff[t] = s[t] - v;   // exclusive
}

__global__ __launch_bounds__(256) void scan_final(const int* __restrict__ deg, const int* __restrict__ boff,
        int* __restrict__ rowstart){
    int t = threadIdx.x, lane = t & 63, w = t >> 6;
    int i = blockIdx.x*256 + t;
    int orig = (i < NN) ? deg[i] : 0;
    int v = orig;
    #pragma unroll
    for (int off = 1; off < 64; off <<= 1){
        int u = __shfl_up(v, off);
        if (lane >= off) v += u;
    }
    __shared__ int ws[4];
    if (lane == 63) ws[w] = v;
    __syncthreads();
    if (t == 0){
        int a = 0;
        #pragma unroll
        for (int j = 0; j < 4; ++j){ int xv = ws[j]; ws[j] = a; a += xv; }
    }
    __syncthreads();
    int excl = (v - orig) + ws[w] + boff[blockIdx.x];
    if (i < NN) rowstart[i] = excl;
    if (i == NN) rowstart[NN] = ETOT;
}

// one block per bucket: scatter into esrc; writes land in bucket's contiguous window
__global__ __launch_bounds__(256) void fine_scatter(const unsigned* __restrict__ packed,
        const int* __restrict__ gboff, const int* __restrict__ rowstart, int* __restrict__ esrc){
    __shared__ int lcur[1 << BSH];
    int b = blockIdx.x, tid = threadIdx.x;
    int n0 = b << BSH;
    if (tid < (1 << BSH)) lcur[tid] = (n0 + tid < NN) ? rowstart[n0 + tid] : 0;
    __syncthreads();
    int p0 = gboff[b], p1 = gboff[b+1];
    for (int i = p0 + tid; i < p1; i += 256){
        unsigned p = packed[i];
        int pos = atomicAdd(&lcur[p & ((1 << BSH) - 1)], 1);
        esrc[pos] = (int)(p >> 16);
    }
}

// ---------------- GEMM v4: k-sliced waves, W in named registers ----------------

__global__ __launch_bounds__(256, 4) void gemm1(const float* __restrict__ x, const float* __restrict__ W1,
        __half* __restrict__ h1h){
    __shared__ float xs[64*144];   // [row][slice ks][36]
    int tid = threadIdx.x;
    int base = blockIdx.x * 64;
    int w = tid >> 6, lane = tid & 63;
    int oL = lane >> 2, ks = lane & 3;
    int o1 = (w & 1)*32 + oL, o2 = o1 + 16;
    float4 wra[8], wrb[8];
    {
        const float4* W4 = reinterpret_cast<const float4*>(W1);
        #pragma unroll
        for (int j4 = 0; j4 < 8; ++j4){
            wra[j4] = W4[o1*32 + ks*8 + j4];
            wrb[j4] = W4[o2*32 + ks*8 + j4];
        }
    }
    {
        #pragma unroll
        for (int j = 0; j < 8; ++j){
            int f = tid + 256*j;
            int row = f >> 5, c4 = f & 31;
            int n = base + row;
            float4 v = make_float4(0.f,0.f,0.f,0.f);
            if (n < NN) v = reinterpret_cast<const float4*>(x)[n*32 + c4];
            int sk = c4 >> 3, j4 = c4 & 7;
            *(float4*)(&xs[row*144 + sk*36 + j4*4]) = v;
        }
    }
    __syncthreads();
    int rbase = (w >> 1) * 32;
    for (int r = 0; r < 32; ++r){
        int row = rbase + r;
        const float* xb = &xs[row*144 + ks*36];
        float acc1 = 0.f, acc2 = 0.f;
        #pragma unroll
        for (int j4 = 0; j4 < 8; ++j4){
            float4 xv = *(const float4*)(xb + j4*4);
            acc1 = fmaf(xv.x, wra[j4].x, acc1);
            acc2 = fmaf(xv.x, wrb[j4].x, acc2);
            acc1 = fmaf(xv.y, wra[j4].y, acc1);
            acc2 = fmaf(xv.y, wrb[j4].y, acc2);
            acc1 = fmaf(xv.z, wra[j4].z, acc1);
            acc2 = fmaf(xv.z, wrb[j4].z, acc2);
            acc1 = fmaf(xv.w, wra[j4].w, acc1);
            acc2 = fmaf(xv.w, wrb[j4].w, acc2);
        }
        acc1 += __shfl_xor(acc1, 1); acc1 += __shfl_xor(acc1, 2);
        acc2 += __shfl_xor(acc2, 1); acc2 += __shfl_xor(acc2, 2);
        int node = base + row;
        if (ks == 0 && node < NN){
            h1h[node*64 + o1] = __float2half(acc1);
            h1h[node*64 + o2] = __float2half(acc2);
        }
    }
}

__global__ __launch_bounds__(256, 4) void gemm2(const float* __restrict__ out1, const float* __restrict__ W2,
        __half* __restrict__ h2h){
    __shared__ float xs[64*80];    // [row][slice ks][20]
    int tid = threadIdx.x;
    int base = blockIdx.x * 64;
    int w = tid >> 6, lane = tid & 63;
    int o = lane >> 2, ks = lane & 3;
    float4 wr[4];
    {
        const float4* W4 = reinterpret_cast<const float4*>(W2);
        #pragma unroll
        for (int j4 = 0; j4 < 4; ++j4)
            wr[j4] = W4[o*16 + ks*4 + j4];
    }
    {
        #pragma unroll
        for (int j = 0; j < 4; ++j){
            int f = tid + 256*j;
            int row = f >> 4, c4 = f & 15;
            int n = base + row;
            float4 v = make_float4(0.f,0.f,0.f,0.f);
            if (n < NN) v = reinterpret_cast<const float4*>(out1)[n*16 + c4];
            v.x = v.x > 0.f ? v.x : __expf(v.x) - 1.f;
            v.y = v.y > 0.f ? v.y : __expf(v.y) - 1.f;
            v.z = v.z > 0.f ? v.z : __expf(v.z) - 1.f;
            v.w = v.w > 0.f ? v.w : __expf(v.w) - 1.f;
            int sk = c4 >> 2, j4 = c4 & 3;
            *(float4*)(&xs[row*80 + sk*20 + j4*4]) = v;
        }
    }
    __syncthreads();
    for (int r = 0; r < 16; ++r){
        int row = w*16 + r;
        const float* xb = &xs[row*80 + ks*20];
        float acc = 0.f;
        #pragma unroll
        for (int j4 = 0; j4 < 4; ++j4){
            float4 xv = *(const float4*)(xb + j4*4);
            acc = fmaf(xv.x, wr[j4].x, acc);
            acc = fmaf(xv.y, wr[j4].y, acc);
            acc = fmaf(xv.z, wr[j4].z, acc);
            acc = fmaf(xv.w, wr[j4].w, acc);
        }
        acc += __shfl_xor(acc, 1); acc += __shfl_xor(acc, 2);
        int node = base + row;
        if (ks == 0 && node < NN)
            h2h[node*16 + o] = __float2half(acc);
    }
}

// ---------------- attention logits from fp16 h ----------------

__global__ __launch_bounds__(256) void att1(const __half* __restrict__ h1h,
        const float* __restrict__ att_s, const float* __restrict__ att_d,
        float* __restrict__ a_src, float* __restrict__ a_dst){
    int idx = blockIdx.x*256 + threadIdx.x;
    if (idx >= NN*NH) return;
    int n = idx >> 3, h = idx & 7;
    float4 raw = reinterpret_cast<const float4*>(h1h)[n*8 + h];
    const __half2* hp = (const __half2*)&raw;
    float ds_ = 0.f, dd_ = 0.f;
    #pragma unroll
    for (int q = 0; q < 4; ++q){
        float2 f = __half22float2(hp[q]);
        ds_ = fmaf(f.x, att_s[h*8 + 2*q],     ds_);
        ds_ = fmaf(f.y, att_s[h*8 + 2*q + 1], ds_);
        dd_ = fmaf(f.x, att_d[h*8 + 2*q],     dd_);
        dd_ = fmaf(f.y, att_d[h*8 + 2*q + 1], dd_);
    }
    a_src[idx] = ds_;
    a_dst[idx] = dd_;
}

__global__ __launch_bounds__(256) void att2(const __half* __restrict__ h2h,
        const float* __restrict__ att_s, const float* __restrict__ att_d,
        float* __restrict__ a_src, float* __restrict__ a_dst){
    int n = blockIdx.x*256 + threadIdx.x;
    if (n >= NN) return;
    float4 r0 = reinterpret_cast<const float4*>(h2h)[n*2];
    float4 r1 = reinterpret_cast<const float4*>(h2h)[n*2 + 1];
    const __half2* hp0 = (const __half2*)&r0;
    const __half2* hp1 = (const __half2*)&r1;
    float ds_ = 0.f, dd_ = 0.f;
    #pragma unroll
    for (int q = 0; q < 4; ++q){
        float2 f = __half22float2(hp0[q]);
        ds_ = fmaf(f.x, att_s[2*q],   ds_); ds_ = fmaf(f.y, att_s[2*q+1], ds_);
        dd_ = fmaf(f.x, att_d[2*q],   dd_); dd_ = fmaf(f.y, att_d[2*q+1], dd_);
    }
    #pragma unroll
    for (int q = 0; q < 4; ++q){
        float2 f = __half22float2(hp1[q]);
        ds_ = fmaf(f.x, att_s[8+2*q], ds_); ds_ = fmaf(f.y, att_s[8+2*q+1], ds_);
        dd_ = fmaf(f.x, att_d[8+2*q], dd_); dd_ = fmaf(f.y, att_d[8+2*q+1], dd_);
    }
    a_src[n] = ds_;
    a_dst[n] = dd_;
}

// ---------------- node-centric aggregation (no-max softmax: e bounded) ----------------

__global__ __launch_bounds__(256) void layer1_node(const int* __restrict__ rowstart,
        const int* __restrict__ esrc, const float* __restrict__ a_src,
        const float* __restrict__ a_dst, const __half* __restrict__ h1h,
        const float* __restrict__ b1, float* __restrict__ out1){
    int wid = (blockIdx.x*256 + threadIdx.x) >> 6;
    int lane = threadIdx.x & 63;
    if (wid >= NN) return;
    int n = wid;
    int h = lane >> 3;
    int r0 = rowstart[n], r1 = rowstart[n+1];
    float ad = a_dst[n*8 + h];
    float den0 = 0.f, acc0 = 0.f, den1 = 0.f, acc1 = 0.f;
    int i = r0;
    for (; i + 1 < r1; i += 2){
        int s0 = esrc[i], s1 = esrc[i+1];
        float e0 = leaky(a_src[s0*8 + h] + ad);
        float e1 = leaky(a_src[s1*8 + h] + ad);
        float hv0 = __half2float(h1h[s0*64 + lane]);
        float hv1 = __half2float(h1h[s1*64 + lane]);
        float p0 = __expf(e0), p1 = __expf(e1);
        den0 += p0; acc0 = fmaf(p0, hv0, acc0);
        den1 += p1; acc1 = fmaf(p1, hv1, acc1);
    }
    if (i < r1){
        int s = esrc[i];
        float p = __expf(leaky(a_src[s*8 + h] + ad));
        den0 += p; acc0 = fmaf(p, __half2float(h1h[s*64 + lane]), acc0);
    }
    float den = den0 + den1, acc = acc0 + acc1;
    out1[n*64 + lane] = acc/(den + 1e-16f) + b1[lane];
}

__global__ __launch_bounds__(256) void layer2_node(const int* __restrict__ rowstart,
        const int* __restrict__ esrc, const float* __restrict__ a_src,
        const float* __restrict__ a_dst, const __half* __restrict__ h2h,
        const float* __restrict__ b2, float* __restrict__ out){
    int wid = (blockIdx.x*256 + threadIdx.x) >> 6;
    int lane = threadIdx.x & 63;
    if (wid >= NN) return;
    int n = wid;
    int slot = lane >> 4, c = lane & 15;
    int r0 = rowstart[n], r1 = rowstart[n+1];
    float ad = a_dst[n];
    float den = 0.f, acc = 0.f;
    for (int i = r0 + slot; i < r1; i += 4){
        int s = esrc[i];
        float p = __expf(leaky(a_src[s] + ad));
        den += p;
        acc = fmaf(p, __half2float(h2h[s*16 + c]), acc);
    }
    den += __shfl_xor(den, 16); den += __shfl_xor(den, 32);
    acc += __shfl_xor(acc, 16); acc += __shfl_xor(acc, 32);
    if (slot == 0) out[n*16 + c] = acc/(den + 1e-16f) + b2[c];
}

extern "C" void kernel_launch(void* const* d_in, const int* in_sizes, int n_in,
                              void* d_out, int out_size, void* d_ws, size_t ws_size,
                              hipStream_t stream){
    const float* x    = (const float*)d_in[0];
    const int*   ei   = (const int*)d_in[1];
    const float* W1   = (const float*)d_in[2];
    const float* as1w = (const float*)d_in[3];
    const float* ad1w = (const float*)d_in[4];
    const float* b1   = (const float*)d_in[5];
    const float* W2   = (const float*)d_in[6];
    const float* as2w = (const float*)d_in[7];
    const float* ad2w = (const float*)d_in[8];
    const float* b2   = (const float*)d_in[9];
    float* out = (float*)d_out;

    float* ws = (float*)d_ws;
    // words: h1h 32N | out1 64N | rowstart N+1 | deg N | bsum NB | boff NB |
    //        gbcnt NBUK | gboff NBUK+1 | gbcur NBUK | packed ETOT | esrc ETOT  (~26.4 MB)
    __half* h1h     = (__half*)ws;                      // 64N halves = 32N words
    float* out1     = ws + (size_t)32*NN;               // 64N
    int*   rowstart = (int*)(ws + (size_t)96*NN);       // N+1
    int*   deg      = rowstart + NN + 1;                // N
    int*   bsum     = deg + NN;                         // NB
    int*   boff     = bsum + NB;                        // NB
    int*   gbcnt    = boff + NB;                        // NBUK
    int*   gboff    = gbcnt + NBUK;                     // NBUK+1
    int*   gbcur    = gboff + NBUK + 1;                 // NBUK
    unsigned* packed= (unsigned*)(gbcur + NBUK);        // ETOT
    int*   esrc     = (int*)(packed + ETOT);            // ETOT
    // a_src1/a_dst1 live in d_out (16N floats) until layer1_node; layer2_node overwrites d_out last
    float* a_src1 = out;                                // 8N
    float* a_dst1 = out + (size_t)8*NN;                 // 8N
    __half* h2h   = h1h;                                // 16N halves (h1h dead after layer1_node)
    float* a_src2 = ws + (size_t)8*NN;                  // N (after h2h's 8N words)
    float* a_dst2 = a_src2 + NN;                        // N

    // CSR build via two-level binning
    hipMemsetAsync(gbcnt, 0, NBUK*sizeof(int), stream);
    hipLaunchKernelGGL(bucket_hist,    dim3(NBLK_A), dim3(256), 0, stream, ei, gbcnt);
    hipLaunchKernelGGL(bucket_scan,    dim3(1), dim3(512), 0, stream, gbcnt, gboff, gbcur);
    hipLaunchKernelGGL(bucket_scatter, dim3(NBLK_A), dim3(256), 0, stream, ei, gbcur, packed);
    hipLaunchKernelGGL(deg_count,      dim3(NBUK), dim3(256), 0, stream, packed, gboff, deg);
    hipLaunchKernelGGL(block_sum,      dim3(NB), dim3(256), 0, stream, deg, bsum);
    hipLaunchKernelGGL(scan_bsum,      dim3(1), dim3(256), 0, stream, bsum, boff);
    hipLaunchKernelGGL(scan_final,     dim3(NB), dim3(256), 0, stream, deg, boff, rowstart);
    hipLaunchKernelGGL(fine_scatter,   dim3(NBUK), dim3(256), 0, stream, packed, gboff, rowstart, esrc);

    // layer 1
    hipLaunchKernelGGL(gemm1, dim3((NN + 63)/64), dim3(256), 0, stream, x, W1, h1h);
    hipLaunchKernelGGL(att1,  dim3((NN*NH + 255)/256), dim3(256), 0, stream, h1h, as1w, ad1w, a_src1, a_dst1);
    hipLaunchKernelGGL(layer1_node, dim3((NN*64 + 255)/256), dim3(256), 0, stream,
                       rowstart, esrc, a_src1, a_dst1, h1h, b1, out1);
    // layer 2
    hipLaunchKernelGGL(gemm2, dim3((NN + 63)/64), dim3(256), 0, stream, out1, W2, h2h);
    hipLaunchKernelGGL(att2,  dim3((NN + 255)/256), dim3(256), 0, stream, h2h, as2w, ad2w, a_src2, a_dst2);
    hipLaunchKernelGGL(layer2_node, dim3((NN*64 + 255)/256), dim3(256), 0, stream,
                       rowstart, esrc, a_src2, a_dst2, h2h, b2, out);
}

// Round 10
// 139.138 us; speedup vs baseline: 5.0765x; 1.2717x over previous
//
#include <hip/hip_runtime.h>
#include <hip/hip_fp16.h>
#include <math.h>

#define NN 50000
#define NE 800000
#define ETOT (NE + NN)
#define INC 128
#define F1 64
#define NH 8
#define OC 16
#define NEG 0.2f
#define BSH 7         // 128 dsts per bucket
#define NBUK 391      // ceil(NN/128)
#define CHUNK_A 4096
#define NBLK_A ((ETOT + CHUNK_A - 1) / CHUNK_A)   // 208

__device__ __forceinline__ float leaky(float x){ return x > 0.f ? x : NEG * x; }

__device__ __forceinline__ void getsd(const int* __restrict__ ei, int e, int& s, int& d){
    if (e < NE){ s = ei[e]; d = ei[NE + e]; }
    else { s = e - NE; d = s; }   // self-loops appended
}

// ---------------- CSR build: two-level binning (no random global atomics) ----------------

__global__ __launch_bounds__(256) void bucket_hist(const int* __restrict__ ei, int* __restrict__ gbcnt){
    __shared__ int bcnt[NBUK];
    int tid = threadIdx.x;
    for (int j = tid; j < NBUK; j += 256) bcnt[j] = 0;
    __syncthreads();
    int e0 = blockIdx.x * CHUNK_A;
    int e1 = e0 + CHUNK_A; if (e1 > ETOT) e1 = ETOT;
    for (int e = e0 + tid; e < e1; e += 256){
        int d = (e < NE) ? ei[NE + e] : e - NE;
        atomicAdd(&bcnt[d >> BSH], 1);
    }
    __syncthreads();
    for (int j = tid; j < NBUK; j += 256)
        if (bcnt[j]) atomicAdd(&gbcnt[j], bcnt[j]);
}

__global__ __launch_bounds__(512) void bucket_scan(const int* __restrict__ gbcnt,
        int* __restrict__ gboff, int* __restrict__ gbcur){
    __shared__ int s[512];
    int t = threadIdx.x;
    int v = (t < NBUK) ? gbcnt[t] : 0;
    s[t] = v; __syncthreads();
    for (int off = 1; off < 512; off <<= 1){
        int u = (t >= off) ? s[t - off] : 0;
        __syncthreads();
        s[t] += u;
        __syncthreads();
    }
    if (t < NBUK){ int ex = s[t] - v; gboff[t] = ex; gbcur[t] = ex; }
    if (t == 0) gboff[NBUK] = ETOT;
}

__global__ __launch_bounds__(256) void bucket_scatter(const int* __restrict__ ei,
        int* __restrict__ gbcur, unsigned* __restrict__ packed){
    __shared__ int bcnt[NBUK];
    int tid = threadIdx.x;
    for (int j = tid; j < NBUK; j += 256) bcnt[j] = 0;
    __syncthreads();
    int e0 = blockIdx.x * CHUNK_A;
    int e1 = e0 + CHUNK_A; if (e1 > ETOT) e1 = ETOT;
    for (int e = e0 + tid; e < e1; e += 256){
        int d = (e < NE) ? ei[NE + e] : e - NE;
        atomicAdd(&bcnt[d >> BSH], 1);
    }
    __syncthreads();
    for (int j = tid; j < NBUK; j += 256){
        int c = bcnt[j];
        bcnt[j] = c ? atomicAdd(&gbcur[j], c) : 0;   // bcnt becomes block-local cursor base
    }
    __syncthreads();
    for (int e = e0 + tid; e < e1; e += 256){
        int s, d; getsd(ei, e, s, d);
        int pos = atomicAdd(&bcnt[d >> BSH], 1);
        packed[pos] = ((unsigned)s << 16) | (unsigned)d;   // s,d < 65536
    }
}

// one block per bucket: LDS deg + 128-wide scan -> rowstart; LDS-cursor scatter -> esrc
__global__ __launch_bounds__(256) void bucket_finalize(const unsigned* __restrict__ packed,
        const int* __restrict__ gboff, int* __restrict__ rowstart, int* __restrict__ esrc){
    __shared__ int ldeg[1 << BSH];
    __shared__ int lcur[1 << BSH];
    __shared__ int wtot[2];
    int b = blockIdx.x, t = threadIdx.x;
    if (t < (1 << BSH)) ldeg[t] = 0;
    __syncthreads();
    int p0 = gboff[b], p1 = gboff[b+1];
    for (int i = p0 + t; i < p1; i += 256)
        atomicAdd(&ldeg[packed[i] & ((1 << BSH) - 1)], 1);
    __syncthreads();
    if (t < (1 << BSH)){
        int v = ldeg[t];
        int lane = t & 63, w = t >> 6;
        int iv = v;
        #pragma unroll
        for (int off = 1; off < 64; off <<= 1){
            int u = __shfl_up(iv, off);
            if (lane >= off) iv += u;
        }
        lcur[t] = iv;                 // wave-inclusive scan (temp)
        if (lane == 63) wtot[w] = iv;
    }
    __syncthreads();
    if (t < (1 << BSH)){
        int v = ldeg[t];
        int w = t >> 6;
        int incl = lcur[t] + (w ? wtot[0] : 0);
        int rs = p0 + incl - v;       // exclusive
        int n = (b << BSH) + t;
        if (n < NN) rowstart[n] = rs;
        lcur[t] = rs;
    }
    if (b == 0 && t == 0) rowstart[NN] = ETOT;
    __syncthreads();
    for (int i = p0 + t; i < p1; i += 256){
        unsigned p = packed[i];
        int pos = atomicAdd(&lcur[p & ((1 << BSH) - 1)], 1);
        esrc[pos] = (int)(p >> 16);
    }
}

// ---------------- GEMM v4: k-sliced waves, W in named registers ----------------

__global__ __launch_bounds__(256, 4) void gemm1(const float* __restrict__ x, const float* __restrict__ W1,
        __half* __restrict__ h1h){
    __shared__ float xs[64*144];   // [row][slice ks][36]
    int tid = threadIdx.x;
    int base = blockIdx.x * 64;
    int w = tid >> 6, lane = tid & 63;
    int oL = lane >> 2, ks = lane & 3;
    int o1 = (w & 1)*32 + oL, o2 = o1 + 16;
    float4 wra[8], wrb[8];
    {
        const float4* W4 = reinterpret_cast<const float4*>(W1);
        #pragma unroll
        for (int j4 = 0; j4 < 8; ++j4){
            wra[j4] = W4[o1*32 + ks*8 + j4];
            wrb[j4] = W4[o2*32 + ks*8 + j4];
        }
    }
    {
        #pragma unroll
        for (int j = 0; j < 8; ++j){
            int f = tid + 256*j;
            int row = f >> 5, c4 = f & 31;
            int n = base + row;
            float4 v = make_float4(0.f,0.f,0.f,0.f);
            if (n < NN) v = reinterpret_cast<const float4*>(x)[n*32 + c4];
            int sk = c4 >> 3, j4 = c4 & 7;
            *(float4*)(&xs[row*144 + sk*36 + j4*4]) = v;
        }
    }
    __syncthreads();
    int rbase = (w >> 1) * 32;
    for (int r = 0; r < 32; ++r){
        int row = rbase + r;
        const float* xb = &xs[row*144 + ks*36];
        float acc1 = 0.f, acc2 = 0.f;
        #pragma unroll
        for (int j4 = 0; j4 < 8; ++j4){
            float4 xv = *(const float4*)(xb + j4*4);
            acc1 = fmaf(xv.x, wra[j4].x, acc1);
            acc2 = fmaf(xv.x, wrb[j4].x, acc2);
            acc1 = fmaf(xv.y, wra[j4].y, acc1);
            acc2 = fmaf(xv.y, wrb[j4].y, acc2);
            acc1 = fmaf(xv.z, wra[j4].z, acc1);
            acc2 = fmaf(xv.z, wrb[j4].z, acc2);
            acc1 = fmaf(xv.w, wra[j4].w, acc1);
            acc2 = fmaf(xv.w, wrb[j4].w, acc2);
        }
        acc1 += __shfl_xor(acc1, 1); acc1 += __shfl_xor(acc1, 2);
        acc2 += __shfl_xor(acc2, 1); acc2 += __shfl_xor(acc2, 2);
        int node = base + row;
        if (ks == 0 && node < NN){
            h1h[node*64 + o1] = __float2half(acc1);
            h1h[node*64 + o2] = __float2half(acc2);
        }
    }
}

__global__ __launch_bounds__(256, 4) void gemm2(const float* __restrict__ out1, const float* __restrict__ W2,
        __half* __restrict__ h2h){
    __shared__ float xs[64*80];    // [row][slice ks][20]
    int tid = threadIdx.x;
    int base = blockIdx.x * 64;
    int w = tid >> 6, lane = tid & 63;
    int o = lane >> 2, ks = lane & 3;
    float4 wr[4];
    {
        const float4* W4 = reinterpret_cast<const float4*>(W2);
        #pragma unroll
        for (int j4 = 0; j4 < 4; ++j4)
            wr[j4] = W4[o*16 + ks*4 + j4];
    }
    {
        #pragma unroll
        for (int j = 0; j < 4; ++j){
            int f = tid + 256*j;
            int row = f >> 4, c4 = f & 15;
            int n = base + row;
            float4 v = make_float4(0.f,0.f,0.f,0.f);
            if (n < NN) v = reinterpret_cast<const float4*>(out1)[n*16 + c4];
            v.x = v.x > 0.f ? v.x : __expf(v.x) - 1.f;
            v.y = v.y > 0.f ? v.y : __expf(v.y) - 1.f;
            v.z = v.z > 0.f ? v.z : __expf(v.z) - 1.f;
            v.w = v.w > 0.f ? v.w : __expf(v.w) - 1.f;
            int sk = c4 >> 2, j4 = c4 & 3;
            *(float4*)(&xs[row*80 + sk*20 + j4*4]) = v;
        }
    }
    __syncthreads();
    for (int r = 0; r < 16; ++r){
        int row = w*16 + r;
        const float* xb = &xs[row*80 + ks*20];
        float acc = 0.f;
        #pragma unroll
        for (int j4 = 0; j4 < 4; ++j4){
            float4 xv = *(const float4*)(xb + j4*4);
            acc = fmaf(xv.x, wr[j4].x, acc);
            acc = fmaf(xv.y, wr[j4].y, acc);
            acc = fmaf(xv.z, wr[j4].z, acc);
            acc = fmaf(xv.w, wr[j4].w, acc);
        }
        acc += __shfl_xor(acc, 1); acc += __shfl_xor(acc, 2);
        int node = base + row;
        if (ks == 0 && node < NN)
            h2h[node*16 + o] = __float2half(acc);
    }
}

// ---------------- attention logits from fp16 h ----------------

__global__ __launch_bounds__(256) void att1(const __half* __restrict__ h1h,
        const float* __restrict__ att_s, const float* __restrict__ att_d,
        float* __restrict__ a_src, float* __restrict__ a_dst){
    int idx = blockIdx.x*256 + threadIdx.x;
    if (idx >= NN*NH) return;
    int n = idx >> 3, h = idx & 7;
    float4 raw = reinterpret_cast<const float4*>(h1h)[n*8 + h];
    const __half2* hp = (const __half2*)&raw;
    float ds_ = 0.f, dd_ = 0.f;
    #pragma unroll
    for (int q = 0; q < 4; ++q){
        float2 f = __half22float2(hp[q]);
        ds_ = fmaf(f.x, att_s[h*8 + 2*q],     ds_);
        ds_ = fmaf(f.y, att_s[h*8 + 2*q + 1], ds_);
        dd_ = fmaf(f.x, att_d[h*8 + 2*q],     dd_);
        dd_ = fmaf(f.y, att_d[h*8 + 2*q + 1], dd_);
    }
    a_src[idx] = ds_;
    a_dst[idx] = dd_;
}

__global__ __launch_bounds__(256) void att2(const __half* __restrict__ h2h,
        const float* __restrict__ att_s, const float* __restrict__ att_d,
        float* __restrict__ a_src, float* __restrict__ a_dst){
    int n = blockIdx.x*256 + threadIdx.x;
    if (n >= NN) return;
    float4 r0 = reinterpret_cast<const float4*>(h2h)[n*2];
    float4 r1 = reinterpret_cast<const float4*>(h2h)[n*2 + 1];
    const __half2* hp0 = (const __half2*)&r0;
    const __half2* hp1 = (const __half2*)&r1;
    float ds_ = 0.f, dd_ = 0.f;
    #pragma unroll
    for (int q = 0; q < 4; ++q){
        float2 f = __half22float2(hp0[q]);
        ds_ = fmaf(f.x, att_s[2*q],   ds_); ds_ = fmaf(f.y, att_s[2*q+1], ds_);
        dd_ = fmaf(f.x, att_d[2*q],   dd_); dd_ = fmaf(f.y, att_d[2*q+1], dd_);
    }
    #pragma unroll
    for (int q = 0; q < 4; ++q){
        float2 f = __half22float2(hp1[q]);
        ds_ = fmaf(f.x, att_s[8+2*q], ds_); ds_ = fmaf(f.y, att_s[8+2*q+1], ds_);
        dd_ = fmaf(f.x, att_d[8+2*q], dd_); dd_ = fmaf(f.y, att_d[8+2*q+1], dd_);
    }
    a_src[n] = ds_;
    a_dst[n] = dd_;
}

// ---------------- node-centric aggregation (no-max softmax: e bounded) ----------------

// one wave per node; lane = h*8+c; unroll-4, wave-uniform node id via readfirstlane
__global__ __launch_bounds__(256) void layer1_node(const int* __restrict__ rowstart,
        const int* __restrict__ esrc, const float* __restrict__ a_src,
        const float* __restrict__ a_dst, const __half* __restrict__ h1h,
        const float* __restrict__ b1, float* __restrict__ out1){
    int wid = __builtin_amdgcn_readfirstlane((blockIdx.x*256 + threadIdx.x) >> 6);
    int lane = threadIdx.x & 63;
    if (wid >= NN) return;
    int n = wid;
    int h = lane >> 3;
    int r0 = rowstart[n], r1 = rowstart[n+1];
    float ad = a_dst[n*8 + h];
    float den0 = 0.f, acc0 = 0.f, den1 = 0.f, acc1 = 0.f;
    float den2 = 0.f, acc2 = 0.f, den3 = 0.f, acc3 = 0.f;
    int i = r0;
    for (; i + 3 < r1; i += 4){
        int s0 = esrc[i], s1 = esrc[i+1], s2 = esrc[i+2], s3 = esrc[i+3];
        float e0 = leaky(a_src[s0*8 + h] + ad);
        float e1 = leaky(a_src[s1*8 + h] + ad);
        float e2 = leaky(a_src[s2*8 + h] + ad);
        float e3 = leaky(a_src[s3*8 + h] + ad);
        float hv0 = __half2float(h1h[s0*64 + lane]);
        float hv1 = __half2float(h1h[s1*64 + lane]);
        float hv2 = __half2float(h1h[s2*64 + lane]);
        float hv3 = __half2float(h1h[s3*64 + lane]);
        float p0 = __expf(e0), p1 = __expf(e1), p2 = __expf(e2), p3 = __expf(e3);
        den0 += p0; acc0 = fmaf(p0, hv0, acc0);
        den1 += p1; acc1 = fmaf(p1, hv1, acc1);
        den2 += p2; acc2 = fmaf(p2, hv2, acc2);
        den3 += p3; acc3 = fmaf(p3, hv3, acc3);
    }
    for (; i < r1; ++i){
        int s = esrc[i];
        float p = __expf(leaky(a_src[s*8 + h] + ad));
        den0 += p; acc0 = fmaf(p, __half2float(h1h[s*64 + lane]), acc0);
    }
    float den = (den0 + den1) + (den2 + den3);
    float acc = (acc0 + acc1) + (acc2 + acc3);
    out1[n*64 + lane] = acc/(den + 1e-16f) + b1[lane];
}

// one wave per node; lane = slot*16 + c; 4 slots x unroll-2 = 8 edges in flight
__global__ __launch_bounds__(256) void layer2_node(const int* __restrict__ rowstart,
        const int* __restrict__ esrc, const float* __restrict__ a_src,
        const float* __restrict__ a_dst, const __half* __restrict__ h2h,
        const float* __restrict__ b2, float* __restrict__ out){
    int wid = __builtin_amdgcn_readfirstlane((blockIdx.x*256 + threadIdx.x) >> 6);
    int lane = threadIdx.x & 63;
    if (wid >= NN) return;
    int n = wid;
    int slot = lane >> 4, c = lane & 15;
    int r0 = rowstart[n], r1 = rowstart[n+1];
    float ad = a_dst[n];
    float den0 = 0.f, acc0 = 0.f, den1 = 0.f, acc1 = 0.f;
    int i = r0 + slot;
    for (; i + 4 < r1; i += 8){
        int s0 = esrc[i], s1 = esrc[i+4];
        float p0 = __expf(leaky(a_src[s0] + ad));
        float p1 = __expf(leaky(a_src[s1] + ad));
        float hv0 = __half2float(h2h[s0*16 + c]);
        float hv1 = __half2float(h2h[s1*16 + c]);
        den0 += p0; acc0 = fmaf(p0, hv0, acc0);
        den1 += p1; acc1 = fmaf(p1, hv1, acc1);
    }
    if (i < r1){
        int s = esrc[i];
        float p = __expf(leaky(a_src[s] + ad));
        den0 += p; acc0 = fmaf(p, __half2float(h2h[s*16 + c]), acc0);
    }
    float den = den0 + den1, acc = acc0 + acc1;
    den += __shfl_xor(den, 16); den += __shfl_xor(den, 32);
    acc += __shfl_xor(acc, 16); acc += __shfl_xor(acc, 32);
    if (slot == 0) out[n*16 + c] = acc/(den + 1e-16f) + b2[c];
}

extern "C" void kernel_launch(void* const* d_in, const int* in_sizes, int n_in,
                              void* d_out, int out_size, void* d_ws, size_t ws_size,
                              hipStream_t stream){
    const float* x    = (const float*)d_in[0];
    const int*   ei   = (const int*)d_in[1];
    const float* W1   = (const float*)d_in[2];
    const float* as1w = (const float*)d_in[3];
    const float* ad1w = (const float*)d_in[4];
    const float* b1   = (const float*)d_in[5];
    const float* W2   = (const float*)d_in[6];
    const float* as2w = (const float*)d_in[7];
    const float* ad2w = (const float*)d_in[8];
    const float* b2   = (const float*)d_in[9];
    float* out = (float*)d_out;

    float* ws = (float*)d_ws;
    // words: h1h 32N | out1 64N | rowstart N+1 | gbcnt NBUK | gboff NBUK+1 | gbcur NBUK |
    //        packed ETOT | esrc ETOT  (~25.9 MB)
    __half* h1h     = (__half*)ws;                      // 64N halves = 32N words
    float* out1     = ws + (size_t)32*NN;               // 64N
    int*   rowstart = (int*)(ws + (size_t)96*NN);       // N+1
    int*   gbcnt    = rowstart + NN + 1;                // NBUK
    int*   gboff    = gbcnt + NBUK;                     // NBUK+1
    int*   gbcur    = gboff + NBUK + 1;                 // NBUK
    unsigned* packed= (unsigned*)(gbcur + NBUK);        // ETOT
    int*   esrc     = (int*)(packed + ETOT);            // ETOT
    // a_src1/a_dst1 live in d_out (16N floats) until layer1_node; layer2_node overwrites d_out last
    float* a_src1 = out;                                // 8N
    float* a_dst1 = out + (size_t)8*NN;                 // 8N
    __half* h2h   = h1h;                                // 16N halves (h1h dead after layer1_node)
    float* a_src2 = ws + (size_t)8*NN;                  // N (after h2h's 8N words)
    float* a_dst2 = a_src2 + NN;                        // N

    // CSR build via two-level binning
    hipMemsetAsync(gbcnt, 0, NBUK*sizeof(int), stream);
    hipLaunchKernelGGL(bucket_hist,     dim3(NBLK_A), dim3(256), 0, stream, ei, gbcnt);
    hipLaunchKernelGGL(bucket_scan,     dim3(1), dim3(512), 0, stream, gbcnt, gboff, gbcur);
    hipLaunchKernelGGL(bucket_scatter,  dim3(NBLK_A), dim3(256), 0, stream, ei, gbcur, packed);
    hipLaunchKernelGGL(bucket_finalize, dim3(NBUK), dim3(256), 0, stream, packed, gboff, rowstart, esrc);

    // layer 1
    hipLaunchKernelGGL(gemm1, dim3((NN + 63)/64), dim3(256), 0, stream, x, W1, h1h);
    hipLaunchKernelGGL(att1,  dim3((NN*NH + 255)/256), dim3(256), 0, stream, h1h, as1w, ad1w, a_src1, a_dst1);
    hipLaunchKernelGGL(layer1_node, dim3((NN*64 + 255)/256), dim3(256), 0, stream,
                       rowstart, esrc, a_src1, a_dst1, h1h, b1, out1);
    // layer 2
    hipLaunchKernelGGL(gemm2, dim3((NN + 63)/64), dim3(256), 0, stream, out1, W2, h2h);
    hipLaunchKernelGGL(att2,  dim3((NN + 255)/256), dim3(256), 0, stream, h2h, as2w, ad2w, a_src2, a_dst2);
    hipLaunchKernelGGL(layer2_node, dim3((NN*64 + 255)/256), dim3(256), 0, stream,
                       rowstart, esrc, a_src2, a_dst2, h2h, b2, out);
}

// Round 11
// 136.872 us; speedup vs baseline: 5.1605x; 1.0166x over previous
//
#include <hip/hip_runtime.h>
#include <hip/hip_fp16.h>
#include <math.h>

#define NN 50000
#define NE 800000
#define ETOT (NE + NN)
#define INC 128
#define F1 64
#define NH 8
#define OC 16
#define NEG 0.2f
#define BSH 7         // 128 dsts per bucket
#define NBUK 391      // ceil(NN/128)
#define CHUNK_A 4096
#define NBLK_A ((ETOT + CHUNK_A - 1) / CHUNK_A)   // 208

__device__ __forceinline__ float leaky(float x){ return x > 0.f ? x : NEG * x; }

__device__ __forceinline__ void getsd(const int* __restrict__ ei, int e, int& s, int& d){
    if (e < NE){ s = ei[e]; d = ei[NE + e]; }
    else { s = e - NE; d = s; }   // self-loops appended
}

// ---------------- CSR build: two-level binning (no random global atomics) ----------------

__global__ __launch_bounds__(256) void zero_gbcnt(int* __restrict__ gbcnt){
    int i = blockIdx.x*256 + threadIdx.x;
    if (i < NBUK) gbcnt[i] = 0;
}

__global__ __launch_bounds__(256) void bucket_hist(const int* __restrict__ ei, int* __restrict__ gbcnt){
    __shared__ int bcnt[NBUK];
    int tid = threadIdx.x;
    for (int j = tid; j < NBUK; j += 256) bcnt[j] = 0;
    __syncthreads();
    int e0 = blockIdx.x * CHUNK_A;
    int e1 = e0 + CHUNK_A; if (e1 > ETOT) e1 = ETOT;
    for (int e = e0 + tid; e < e1; e += 256){
        int d = (e < NE) ? ei[NE + e] : e - NE;
        atomicAdd(&bcnt[d >> BSH], 1);
    }
    __syncthreads();
    for (int j = tid; j < NBUK; j += 256)
        if (bcnt[j]) atomicAdd(&gbcnt[j], bcnt[j]);
}

__global__ __launch_bounds__(512) void bucket_scan(const int* __restrict__ gbcnt,
        int* __restrict__ gboff, int* __restrict__ gbcur){
    __shared__ int s[512];
    int t = threadIdx.x;
    int v = (t < NBUK) ? gbcnt[t] : 0;
    s[t] = v; __syncthreads();
    for (int off = 1; off < 512; off <<= 1){
        int u = (t >= off) ? s[t - off] : 0;
        __syncthreads();
        s[t] += u;
        __syncthreads();
    }
    if (t < NBUK){ int ex = s[t] - v; gboff[t] = ex; gbcur[t] = ex; }
    if (t == 0) gboff[NBUK] = ETOT;
}

__global__ __launch_bounds__(256) void bucket_scatter(const int* __restrict__ ei,
        int* __restrict__ gbcur, unsigned* __restrict__ packed){
    __shared__ int bcnt[NBUK];
    int tid = threadIdx.x;
    for (int j = tid; j < NBUK; j += 256) bcnt[j] = 0;
    __syncthreads();
    int e0 = blockIdx.x * CHUNK_A;
    int e1 = e0 + CHUNK_A; if (e1 > ETOT) e1 = ETOT;
    for (int e = e0 + tid; e < e1; e += 256){
        int d = (e < NE) ? ei[NE + e] : e - NE;
        atomicAdd(&bcnt[d >> BSH], 1);
    }
    __syncthreads();
    for (int j = tid; j < NBUK; j += 256){
        int c = bcnt[j];
        bcnt[j] = c ? atomicAdd(&gbcur[j], c) : 0;   // bcnt becomes block-local cursor base
    }
    __syncthreads();
    for (int e = e0 + tid; e < e1; e += 256){
        int s, d; getsd(ei, e, s, d);
        int pos = atomicAdd(&bcnt[d >> BSH], 1);
        packed[pos] = ((unsigned)s << 16) | (unsigned)d;   // s,d < 65536
    }
}

// one block per bucket: LDS deg + 128-wide scan -> rowstart; LDS-cursor scatter -> esrc
__global__ __launch_bounds__(256) void bucket_finalize(const unsigned* __restrict__ packed,
        const int* __restrict__ gboff, int* __restrict__ rowstart, int* __restrict__ esrc){
    __shared__ int ldeg[1 << BSH];
    __shared__ int lcur[1 << BSH];
    __shared__ int wtot[2];
    int b = blockIdx.x, t = threadIdx.x;
    if (t < (1 << BSH)) ldeg[t] = 0;
    __syncthreads();
    int p0 = gboff[b], p1 = gboff[b+1];
    for (int i = p0 + t; i < p1; i += 256)
        atomicAdd(&ldeg[packed[i] & ((1 << BSH) - 1)], 1);
    __syncthreads();
    if (t < (1 << BSH)){
        int v = ldeg[t];
        int lane = t & 63, w = t >> 6;
        int iv = v;
        #pragma unroll
        for (int off = 1; off < 64; off <<= 1){
            int u = __shfl_up(iv, off);
            if (lane >= off) iv += u;
        }
        lcur[t] = iv;                 // wave-inclusive scan (temp)
        if (lane == 63) wtot[w] = iv;
    }
    __syncthreads();
    if (t < (1 << BSH)){
        int v = ldeg[t];
        int w = t >> 6;
        int incl = lcur[t] + (w ? wtot[0] : 0);
        int rs = p0 + incl - v;       // exclusive
        int n = (b << BSH) + t;
        if (n < NN) rowstart[n] = rs;
        lcur[t] = rs;
    }
    if (b == 0 && t == 0) rowstart[NN] = ETOT;
    __syncthreads();
    for (int i = p0 + t; i < p1; i += 256){
        unsigned p = packed[i];
        int pos = atomicAdd(&lcur[p & ((1 << BSH) - 1)], 1);
        esrc[pos] = (int)(p >> 16);
    }
}

// ---------------- GEMM v4: k-sliced waves, W in named registers ----------------

__global__ __launch_bounds__(256, 4) void gemm1(const float* __restrict__ x, const float* __restrict__ W1,
        __half* __restrict__ h1h){
    __shared__ float xs[64*144];   // [row][slice ks][36]
    int tid = threadIdx.x;
    int base = blockIdx.x * 64;
    int w = tid >> 6, lane = tid & 63;
    int oL = lane >> 2, ks = lane & 3;
    int o1 = (w & 1)*32 + oL, o2 = o1 + 16;
    float4 wra[8], wrb[8];
    {
        const float4* W4 = reinterpret_cast<const float4*>(W1);
        #pragma unroll
        for (int j4 = 0; j4 < 8; ++j4){
            wra[j4] = W4[o1*32 + ks*8 + j4];
            wrb[j4] = W4[o2*32 + ks*8 + j4];
        }
    }
    {
        #pragma unroll
        for (int j = 0; j < 8; ++j){
            int f = tid + 256*j;
            int row = f >> 5, c4 = f & 31;
            int n = base + row;
            float4 v = make_float4(0.f,0.f,0.f,0.f);
            if (n < NN) v = reinterpret_cast<const float4*>(x)[n*32 + c4];
            int sk = c4 >> 3, j4 = c4 & 7;
            *(float4*)(&xs[row*144 + sk*36 + j4*4]) = v;
        }
    }
    __syncthreads();
    int rbase = (w >> 1) * 32;
    for (int r = 0; r < 32; ++r){
        int row = rbase + r;
        const float* xb = &xs[row*144 + ks*36];
        float acc1 = 0.f, acc2 = 0.f;
        #pragma unroll
        for (int j4 = 0; j4 < 8; ++j4){
            float4 xv = *(const float4*)(xb + j4*4);
            acc1 = fmaf(xv.x, wra[j4].x, acc1);
            acc2 = fmaf(xv.x, wrb[j4].x, acc2);
            acc1 = fmaf(xv.y, wra[j4].y, acc1);
            acc2 = fmaf(xv.y, wrb[j4].y, acc2);
            acc1 = fmaf(xv.z, wra[j4].z, acc1);
            acc2 = fmaf(xv.z, wrb[j4].z, acc2);
            acc1 = fmaf(xv.w, wra[j4].w, acc1);
            acc2 = fmaf(xv.w, wrb[j4].w, acc2);
        }
        acc1 += __shfl_xor(acc1, 1); acc1 += __shfl_xor(acc1, 2);
        acc2 += __shfl_xor(acc2, 1); acc2 += __shfl_xor(acc2, 2);
        int node = base + row;
        if (ks == 0 && node < NN){
            h1h[node*64 + o1] = __float2half(acc1);
            h1h[node*64 + o2] = __float2half(acc2);
        }
    }
}

__global__ __launch_bounds__(256, 4) void gemm2(const float* __restrict__ out1, const float* __restrict__ W2,
        __half* __restrict__ h2h){
    __shared__ float xs[64*80];    // [row][slice ks][20]
    int tid = threadIdx.x;
    int base = blockIdx.x * 64;
    int w = tid >> 6, lane = tid & 63;
    int o = lane >> 2, ks = lane & 3;
    float4 wr[4];
    {
        const float4* W4 = reinterpret_cast<const float4*>(W2);
        #pragma unroll
        for (int j4 = 0; j4 < 4; ++j4)
            wr[j4] = W4[o*16 + ks*4 + j4];
    }
    {
        #pragma unroll
        for (int j = 0; j < 4; ++j){
            int f = tid + 256*j;
            int row = f >> 4, c4 = f & 15;
            int n = base + row;
            float4 v = make_float4(0.f,0.f,0.f,0.f);
            if (n < NN) v = reinterpret_cast<const float4*>(out1)[n*16 + c4];
            v.x = v.x > 0.f ? v.x : __expf(v.x) - 1.f;
            v.y = v.y > 0.f ? v.y : __expf(v.y) - 1.f;
            v.z = v.z > 0.f ? v.z : __expf(v.z) - 1.f;
            v.w = v.w > 0.f ? v.w : __expf(v.w) - 1.f;
            int sk = c4 >> 2, j4 = c4 & 3;
            *(float4*)(&xs[row*80 + sk*20 + j4*4]) = v;
        }
    }
    __syncthreads();
    for (int r = 0; r < 16; ++r){
        int row = w*16 + r;
        const float* xb = &xs[row*80 + ks*20];
        float acc = 0.f;
        #pragma unroll
        for (int j4 = 0; j4 < 4; ++j4){
            float4 xv = *(const float4*)(xb + j4*4);
            acc = fmaf(xv.x, wr[j4].x, acc);
            acc = fmaf(xv.y, wr[j4].y, acc);
            acc = fmaf(xv.z, wr[j4].z, acc);
            acc = fmaf(xv.w, wr[j4].w, acc);
        }
        acc += __shfl_xor(acc, 1); acc += __shfl_xor(acc, 2);
        int node = base + row;
        if (ks == 0 && node < NN)
            h2h[node*16 + o] = __float2half(acc);
    }
}

// ---------------- attention logits from fp16 h ----------------

__global__ __launch_bounds__(256) void att1(const __half* __restrict__ h1h,
        const float* __restrict__ att_s, const float* __restrict__ att_d,
        float* __restrict__ a_src, float* __restrict__ a_dst){
    int idx = blockIdx.x*256 + threadIdx.x;
    if (idx >= NN*NH) return;
    int n = idx >> 3, h = idx & 7;
    float4 raw = reinterpret_cast<const float4*>(h1h)[n*8 + h];
    const __half2* hp = (const __half2*)&raw;
    float ds_ = 0.f, dd_ = 0.f;
    #pragma unroll
    for (int q = 0; q < 4; ++q){
        float2 f = __half22float2(hp[q]);
        ds_ = fmaf(f.x, att_s[h*8 + 2*q],     ds_);
        ds_ = fmaf(f.y, att_s[h*8 + 2*q + 1], ds_);
        dd_ = fmaf(f.x, att_d[h*8 + 2*q],     dd_);
        dd_ = fmaf(f.y, att_d[h*8 + 2*q + 1], dd_);
    }
    a_src[idx] = ds_;
    a_dst[idx] = dd_;
}

__global__ __launch_bounds__(256) void att2(const __half* __restrict__ h2h,
        const float* __restrict__ att_s, const float* __restrict__ att_d,
        float* __restrict__ a_src, float* __restrict__ a_dst){
    int n = blockIdx.x*256 + threadIdx.x;
    if (n >= NN) return;
    float4 r0 = reinterpret_cast<const float4*>(h2h)[n*2];
    float4 r1 = reinterpret_cast<const float4*>(h2h)[n*2 + 1];
    const __half2* hp0 = (const __half2*)&r0;
    const __half2* hp1 = (const __half2*)&r1;
    float ds_ = 0.f, dd_ = 0.f;
    #pragma unroll
    for (int q = 0; q < 4; ++q){
        float2 f = __half22float2(hp0[q]);
        ds_ = fmaf(f.x, att_s[2*q],   ds_); ds_ = fmaf(f.y, att_s[2*q+1], ds_);
        dd_ = fmaf(f.x, att_d[2*q],   dd_); dd_ = fmaf(f.y, att_d[2*q+1], dd_);
    }
    #pragma unroll
    for (int q = 0; q < 4; ++q){
        float2 f = __half22float2(hp1[q]);
        ds_ = fmaf(f.x, att_s[8+2*q], ds_); ds_ = fmaf(f.y, att_s[8+2*q+1], ds_);
        dd_ = fmaf(f.x, att_d[8+2*q], dd_); dd_ = fmaf(f.y, att_d[8+2*q+1], dd_);
    }
    a_src[n] = ds_;
    a_dst[n] = dd_;
}

// ---------------- node-centric aggregation (no-max softmax: e bounded) ----------------

// one wave per node; lane = h*8+c; unroll-4, wave-uniform node id via readfirstlane
__global__ __launch_bounds__(256) void layer1_node(const int* __restrict__ rowstart,
        const int* __restrict__ esrc, const float* __restrict__ a_src,
        const float* __restrict__ a_dst, const __half* __restrict__ h1h,
        const float* __restrict__ b1, float* __restrict__ out1){
    int wid = __builtin_amdgcn_readfirstlane((blockIdx.x*256 + threadIdx.x) >> 6);
    int lane = threadIdx.x & 63;
    if (wid >= NN) return;
    int n = wid;
    int h = lane >> 3;
    int r0 = rowstart[n], r1 = rowstart[n+1];
    float ad = a_dst[n*8 + h];
    float den0 = 0.f, acc0 = 0.f, den1 = 0.f, acc1 = 0.f;
    float den2 = 0.f, acc2 = 0.f, den3 = 0.f, acc3 = 0.f;
    int i = r0;
    for (; i + 3 < r1; i += 4){
        int s0 = esrc[i], s1 = esrc[i+1], s2 = esrc[i+2], s3 = esrc[i+3];
        float e0 = leaky(a_src[s0*8 + h] + ad);
        float e1 = leaky(a_src[s1*8 + h] + ad);
        float e2 = leaky(a_src[s2*8 + h] + ad);
        float e3 = leaky(a_src[s3*8 + h] + ad);
        float hv0 = __half2float(h1h[s0*64 + lane]);
        float hv1 = __half2float(h1h[s1*64 + lane]);
        float hv2 = __half2float(h1h[s2*64 + lane]);
        float hv3 = __half2float(h1h[s3*64 + lane]);
        float p0 = __expf(e0), p1 = __expf(e1), p2 = __expf(e2), p3 = __expf(e3);
        den0 += p0; acc0 = fmaf(p0, hv0, acc0);
        den1 += p1; acc1 = fmaf(p1, hv1, acc1);
        den2 += p2; acc2 = fmaf(p2, hv2, acc2);
        den3 += p3; acc3 = fmaf(p3, hv3, acc3);
    }
    for (; i < r1; ++i){
        int s = esrc[i];
        float p = __expf(leaky(a_src[s*8 + h] + ad));
        den0 += p; acc0 = fmaf(p, __half2float(h1h[s*64 + lane]), acc0);
    }
    float den = (den0 + den1) + (den2 + den3);
    float acc = (acc0 + acc1) + (acc2 + acc3);
    out1[n*64 + lane] = acc/(den + 1e-16f) + b1[lane];
}

// one wave per node; lane = slot*16 + c; 4 slots x unroll-2 = 8 edges in flight
__global__ __launch_bounds__(256) void layer2_node(const int* __restrict__ rowstart,
        const int* __restrict__ esrc, const float* __restrict__ a_src,
        const float* __restrict__ a_dst, const __half* __restrict__ h2h,
        const float* __restrict__ b2, float* __restrict__ out){
    int wid = __builtin_amdgcn_readfirstlane((blockIdx.x*256 + threadIdx.x) >> 6);
    int lane = threadIdx.x & 63;
    if (wid >= NN) return;
    int n = wid;
    int slot = lane >> 4, c = lane & 15;
    int r0 = rowstart[n], r1 = rowstart[n+1];
    float ad = a_dst[n];
    float den0 = 0.f, acc0 = 0.f, den1 = 0.f, acc1 = 0.f;
    int i = r0 + slot;
    for (; i + 4 < r1; i += 8){
        int s0 = esrc[i], s1 = esrc[i+4];
        float p0 = __expf(leaky(a_src[s0] + ad));
        float p1 = __expf(leaky(a_src[s1] + ad));
        float hv0 = __half2float(h2h[s0*16 + c]);
        float hv1 = __half2float(h2h[s1*16 + c]);
        den0 += p0; acc0 = fmaf(p0, hv0, acc0);
        den1 += p1; acc1 = fmaf(p1, hv1, acc1);
    }
    if (i < r1){
        int s = esrc[i];
        float p = __expf(leaky(a_src[s] + ad));
        den0 += p; acc0 = fmaf(p, __half2float(h2h[s*16 + c]), acc0);
    }
    float den = den0 + den1, acc = acc0 + acc1;
    den += __shfl_xor(den, 16); den += __shfl_xor(den, 32);
    acc += __shfl_xor(acc, 16); acc += __shfl_xor(acc, 32);
    if (slot == 0) out[n*16 + c] = acc/(den + 1e-16f) + b2[c];
}

extern "C" void kernel_launch(void* const* d_in, const int* in_sizes, int n_in,
                              void* d_out, int out_size, void* d_ws, size_t ws_size,
                              hipStream_t stream){
    const float* x    = (const float*)d_in[0];
    const int*   ei   = (const int*)d_in[1];
    const float* W1   = (const float*)d_in[2];
    const float* as1w = (const float*)d_in[3];
    const float* ad1w = (const float*)d_in[4];
    const float* b1   = (const float*)d_in[5];
    const float* W2   = (const float*)d_in[6];
    const float* as2w = (const float*)d_in[7];
    const float* ad2w = (const float*)d_in[8];
    const float* b2   = (const float*)d_in[9];
    float* out = (float*)d_out;

    float* ws = (float*)d_ws;
    // words: h1h 32N | out1 64N | rowstart N+1 | gbcnt NBUK | gboff NBUK+1 | gbcur NBUK |
    //        packed ETOT | esrc ETOT  (~25.9 MB)
    __half* h1h     = (__half*)ws;                      // 64N halves = 32N words
    float* out1     = ws + (size_t)32*NN;               // 64N
    int*   rowstart = (int*)(ws + (size_t)96*NN);       // N+1
    int*   gbcnt    = rowstart + NN + 1;                // NBUK
    int*   gboff    = gbcnt + NBUK;                     // NBUK+1
    int*   gbcur    = gboff + NBUK + 1;                 // NBUK
    unsigned* packed= (unsigned*)(gbcur + NBUK);        // ETOT
    int*   esrc     = (int*)(packed + ETOT);            // ETOT
    // a_src1/a_dst1 live in d_out (16N floats) until layer1_node; layer2_node overwrites d_out last
    float* a_src1 = out;                                // 8N
    float* a_dst1 = out + (size_t)8*NN;                 // 8N
    __half* h2h   = h1h;                                // 16N halves (h1h dead after layer1_node)
    float* a_src2 = ws + (size_t)8*NN;                  // N (after h2h's 8N words)
    float* a_dst2 = a_src2 + NN;                        // N

    // CSR build via two-level binning
    hipLaunchKernelGGL(zero_gbcnt,      dim3(2), dim3(256), 0, stream, gbcnt);
    hipLaunchKernelGGL(bucket_hist,     dim3(NBLK_A), dim3(256), 0, stream, ei, gbcnt);
    hipLaunchKernelGGL(bucket_scan,     dim3(1), dim3(512), 0, stream, gbcnt, gboff, gbcur);
    hipLaunchKernelGGL(bucket_scatter,  dim3(NBLK_A), dim3(256), 0, stream, ei, gbcur, packed);
    hipLaunchKernelGGL(bucket_finalize, dim3(NBUK), dim3(256), 0, stream, packed, gboff, rowstart, esrc);

    // layer 1
    hipLaunchKernelGGL(gemm1, dim3((NN + 63)/64), dim3(256), 0, stream, x, W1, h1h);
    hipLaunchKernelGGL(att1,  dim3((NN*NH + 255)/256), dim3(256), 0, stream, h1h, as1w, ad1w, a_src1, a_dst1);
    hipLaunchKernelGGL(layer1_node, dim3((NN*64 + 255)/256), dim3(256), 0, stream,
                       rowstart, esrc, a_src1, a_dst1, h1h, b1, out1);
    // layer 2
    hipLaunchKernelGGL(gemm2, dim3((NN + 63)/64), dim3(256), 0, stream, out1, W2, h2h);
    hipLaunchKernelGGL(att2,  dim3((NN + 255)/256), dim3(256), 0, stream, h2h, as2w, ad2w, a_src2, a_dst2);
    hipLaunchKernelGGL(layer2_node, dim3((NN*64 + 255)/256), dim3(256), 0, stream,
                       rowstart, esrc, a_src2, a_dst2, h2h, b2, out);
}

// Round 13
// 135.057 us; speedup vs baseline: 5.2299x; 1.0134x over previous
//
#include <hip/hip_runtime.h>
#include <hip/hip_fp16.h>
#include <math.h>

#define NN 50000
#define NE 800000
#define ETOT (NE + NN)
#define INC 128
#define F1 64
#define NH 8
#define OC 16
#define NEG 0.2f
#define BSH 7         // 128 dsts per bucket
#define NBUK 391      // ceil(NN/128)
#define CHUNK_A 4096
#define NBLK_A ((ETOT + CHUNK_A - 1) / CHUNK_A)   // 208

__device__ __forceinline__ float leaky(float x){ return x > 0.f ? x : NEG * x; }

__device__ __forceinline__ void getsd(const int* __restrict__ ei, int e, int& s, int& d){
    if (e < NE){ s = ei[e]; d = ei[NE + e]; }
    else { s = e - NE; d = s; }   // self-loops appended
}

// ---------------- CSR build: two-level binning (R11-proven) ----------------

__global__ __launch_bounds__(256) void zero_gbcnt(int* __restrict__ gbcnt){
    int i = blockIdx.x*256 + threadIdx.x;
    if (i < NBUK) gbcnt[i] = 0;
}

__global__ __launch_bounds__(256) void bucket_hist(const int* __restrict__ ei, int* __restrict__ gbcnt){
    __shared__ int bcnt[NBUK];
    int tid = threadIdx.x;
    for (int j = tid; j < NBUK; j += 256) bcnt[j] = 0;
    __syncthreads();
    int e0 = blockIdx.x * CHUNK_A;
    int e1 = e0 + CHUNK_A; if (e1 > ETOT) e1 = ETOT;
    for (int e = e0 + tid; e < e1; e += 256){
        int d = (e < NE) ? ei[NE + e] : e - NE;
        atomicAdd(&bcnt[d >> BSH], 1);
    }
    __syncthreads();
    for (int j = tid; j < NBUK; j += 256)
        if (bcnt[j]) atomicAdd(&gbcnt[j], bcnt[j]);
}

__global__ __launch_bounds__(512) void bucket_scan(const int* __restrict__ gbcnt,
        int* __restrict__ gboff, int* __restrict__ gbcur){
    __shared__ int s[512];
    int t = threadIdx.x;
    int v = (t < NBUK) ? gbcnt[t] : 0;
    s[t] = v; __syncthreads();
    for (int off = 1; off < 512; off <<= 1){
        int u = (t >= off) ? s[t - off] : 0;
        __syncthreads();
        s[t] += u;
        __syncthreads();
    }
    if (t < NBUK){ int ex = s[t] - v; gboff[t] = ex; gbcur[t] = ex; }
    if (t == 0) gboff[NBUK] = ETOT;
}

__global__ __launch_bounds__(256) void bucket_scatter(const int* __restrict__ ei,
        int* __restrict__ gbcur, unsigned* __restrict__ packed){
    __shared__ int bcnt[NBUK];
    int tid = threadIdx.x;
    for (int j = tid; j < NBUK; j += 256) bcnt[j] = 0;
    __syncthreads();
    int e0 = blockIdx.x * CHUNK_A;
    int e1 = e0 + CHUNK_A; if (e1 > ETOT) e1 = ETOT;
    for (int e = e0 + tid; e < e1; e += 256){
        int d = (e < NE) ? ei[NE + e] : e - NE;
        atomicAdd(&bcnt[d >> BSH], 1);
    }
    __syncthreads();
    for (int j = tid; j < NBUK; j += 256){
        int c = bcnt[j];
        bcnt[j] = c ? atomicAdd(&gbcur[j], c) : 0;   // bcnt becomes block-local cursor base
    }
    __syncthreads();
    for (int e = e0 + tid; e < e1; e += 256){
        int s, d; getsd(ei, e, s, d);
        int pos = atomicAdd(&bcnt[d >> BSH], 1);
        packed[pos] = ((unsigned)s << 16) | (unsigned)d;   // s,d < 65536
    }
}

// one block per bucket: LDS deg + 128-wide scan -> rowstart; LDS-cursor scatter -> esrc
__global__ __launch_bounds__(256) void bucket_finalize(const unsigned* __restrict__ packed,
        const int* __restrict__ gboff, int* __restrict__ rowstart, int* __restrict__ esrc){
    __shared__ int ldeg[1 << BSH];
    __shared__ int lcur[1 << BSH];
    __shared__ int wtot[2];
    int b = blockIdx.x, t = threadIdx.x;
    if (t < (1 << BSH)) ldeg[t] = 0;
    __syncthreads();
    int p0 = gboff[b], p1 = gboff[b+1];
    for (int i = p0 + t; i < p1; i += 256)
        atomicAdd(&ldeg[packed[i] & ((1 << BSH) - 1)], 1);
    __syncthreads();
    if (t < (1 << BSH)){
        int v = ldeg[t];
        int lane = t & 63, w = t >> 6;
        int iv = v;
        #pragma unroll
        for (int off = 1; off < 64; off <<= 1){
            int u = __shfl_up(iv, off);
            if (lane >= off) iv += u;
        }
        lcur[t] = iv;                 // wave-inclusive scan (temp)
        if (lane == 63) wtot[w] = iv;
    }
    __syncthreads();
    if (t < (1 << BSH)){
        int v = ldeg[t];
        int w = t >> 6;
        int incl = lcur[t] + (w ? wtot[0] : 0);
        int rs = p0 + incl - v;       // exclusive
        int n = (b << BSH) + t;
        if (n < NN) rowstart[n] = rs;
        lcur[t] = rs;
    }
    if (b == 0 && t == 0) rowstart[NN] = ETOT;
    __syncthreads();
    for (int i = p0 + t; i < p1; i += 256){
        unsigned p = packed[i];
        int pos = atomicAdd(&lcur[p & ((1 << BSH) - 1)], 1);
        esrc[pos] = (int)(p >> 16);
    }
}

// ---------------- GEMM v4: k-sliced waves, W in named registers ----------------

__global__ __launch_bounds__(256, 4) void gemm1(const float* __restrict__ x, const float* __restrict__ W1,
        __half* __restrict__ h1h){
    __shared__ float xs[64*144];   // [row][slice ks][36]
    int tid = threadIdx.x;
    int base = blockIdx.x * 64;
    int w = tid >> 6, lane = tid & 63;
    int oL = lane >> 2, ks = lane & 3;
    int o1 = (w & 1)*32 + oL, o2 = o1 + 16;
    float4 wra[8], wrb[8];
    {
        const float4* W4 = reinterpret_cast<const float4*>(W1);
        #pragma unroll
        for (int j4 = 0; j4 < 8; ++j4){
            wra[j4] = W4[o1*32 + ks*8 + j4];
            wrb[j4] = W4[o2*32 + ks*8 + j4];
        }
    }
    {
        #pragma unroll
        for (int j = 0; j < 8; ++j){
            int f = tid + 256*j;
            int row = f >> 5, c4 = f & 31;
            int n = base + row;
            float4 v = make_float4(0.f,0.f,0.f,0.f);
            if (n < NN) v = reinterpret_cast<const float4*>(x)[n*32 + c4];
            int sk = c4 >> 3, j4 = c4 & 7;
            *(float4*)(&xs[row*144 + sk*36 + j4*4]) = v;
        }
    }
    __syncthreads();
    int rbase = (w >> 1) * 32;
    for (int r = 0; r < 32; ++r){
        int row = rbase + r;
        const float* xb = &xs[row*144 + ks*36];
        float acc1 = 0.f, acc2 = 0.f;
        #pragma unroll
        for (int j4 = 0; j4 < 8; ++j4){
            float4 xv = *(const float4*)(xb + j4*4);
            acc1 = fmaf(xv.x, wra[j4].x, acc1);
            acc2 = fmaf(xv.x, wrb[j4].x, acc2);
            acc1 = fmaf(xv.y, wra[j4].y, acc1);
            acc2 = fmaf(xv.y, wrb[j4].y, acc2);
            acc1 = fmaf(xv.z, wra[j4].z, acc1);
            acc2 = fmaf(xv.z, wrb[j4].z, acc2);
            acc1 = fmaf(xv.w, wra[j4].w, acc1);
            acc2 = fmaf(xv.w, wrb[j4].w, acc2);
        }
        acc1 += __shfl_xor(acc1, 1); acc1 += __shfl_xor(acc1, 2);
        acc2 += __shfl_xor(acc2, 1); acc2 += __shfl_xor(acc2, 2);
        int node = base + row;
        if (ks == 0 && node < NN){
            h1h[node*64 + o1] = __float2half(acc1);
            h1h[node*64 + o2] = __float2half(acc2);
        }
    }
}

__global__ __launch_bounds__(256, 4) void gemm2(const float* __restrict__ out1, const float* __restrict__ W2,
        __half* __restrict__ h2h){
    __shared__ float xs[64*80];    // [row][slice ks][20]
    int tid = threadIdx.x;
    int base = blockIdx.x * 64;
    int w = tid >> 6, lane = tid & 63;
    int o = lane >> 2, ks = lane & 3;
    float4 wr[4];
    {
        const float4* W4 = reinterpret_cast<const float4*>(W2);
        #pragma unroll
        for (int j4 = 0; j4 < 4; ++j4)
            wr[j4] = W4[o*16 + ks*4 + j4];
    }
    {
        #pragma unroll
        for (int j = 0; j < 4; ++j){
            int f = tid + 256*j;
            int row = f >> 4, c4 = f & 15;
            int n = base + row;
            float4 v = make_float4(0.f,0.f,0.f,0.f);
            if (n < NN) v = reinterpret_cast<const float4*>(out1)[n*16 + c4];
            v.x = v.x > 0.f ? v.x : __expf(v.x) - 1.f;
            v.y = v.y > 0.f ? v.y : __expf(v.y) - 1.f;
            v.z = v.z > 0.f ? v.z : __expf(v.z) - 1.f;
            v.w = v.w > 0.f ? v.w : __expf(v.w) - 1.f;
            int sk = c4 >> 2, j4 = c4 & 3;
            *(float4*)(&xs[row*80 + sk*20 + j4*4]) = v;
        }
    }
    __syncthreads();
    for (int r = 0; r < 16; ++r){
        int row = w*16 + r;
        const float* xb = &xs[row*80 + ks*20];
        float acc = 0.f;
        #pragma unroll
        for (int j4 = 0; j4 < 4; ++j4){
            float4 xv = *(const float4*)(xb + j4*4);
            acc = fmaf(xv.x, wr[j4].x, acc);
            acc = fmaf(xv.y, wr[j4].y, acc);
            acc = fmaf(xv.z, wr[j4].z, acc);
            acc = fmaf(xv.w, wr[j4].w, acc);
        }
        acc += __shfl_xor(acc, 1); acc += __shfl_xor(acc, 2);
        int node = base + row;
        if (ks == 0 && node < NN)
            h2h[node*16 + o] = __float2half(acc);
    }
}

// ---------------- attention logits from fp16 h ----------------

__global__ __launch_bounds__(256) void att1(const __half* __restrict__ h1h,
        const float* __restrict__ att_s, const float* __restrict__ att_d,
        float* __restrict__ a_src, float* __restrict__ a_dst){
    int idx = blockIdx.x*256 + threadIdx.x;
    if (idx >= NN*NH) return;
    int n = idx >> 3, h = idx & 7;
    float4 raw = reinterpret_cast<const float4*>(h1h)[n*8 + h];
    const __half2* hp = (const __half2*)&raw;
    float ds_ = 0.f, dd_ = 0.f;
    #pragma unroll
    for (int q = 0; q < 4; ++q){
        float2 f = __half22float2(hp[q]);
        ds_ = fmaf(f.x, att_s[h*8 + 2*q],     ds_);
        ds_ = fmaf(f.y, att_s[h*8 + 2*q + 1], ds_);
        dd_ = fmaf(f.x, att_d[h*8 + 2*q],     dd_);
        dd_ = fmaf(f.y, att_d[h*8 + 2*q + 1], dd_);
    }
    a_src[idx] = ds_;
    a_dst[idx] = dd_;
}

__global__ __launch_bounds__(256) void att2(const __half* __restrict__ h2h,
        const float* __restrict__ att_s, const float* __restrict__ att_d,
        float* __restrict__ a_src, float* __restrict__ a_dst){
    int n = blockIdx.x*256 + threadIdx.x;
    if (n >= NN) return;
    float4 r0 = reinterpret_cast<const float4*>(h2h)[n*2];
    float4 r1 = reinterpret_cast<const float4*>(h2h)[n*2 + 1];
    const __half2* hp0 = (const __half2*)&r0;
    const __half2* hp1 = (const __half2*)&r1;
    float ds_ = 0.f, dd_ = 0.f;
    #pragma unroll
    for (int q = 0; q < 4; ++q){
        float2 f = __half22float2(hp0[q]);
        ds_ = fmaf(f.x, att_s[2*q],   ds_); ds_ = fmaf(f.y, att_s[2*q+1], ds_);
        dd_ = fmaf(f.x, att_d[2*q],   dd_); dd_ = fmaf(f.y, att_d[2*q+1], dd_);
    }
    #pragma unroll
    for (int q = 0; q < 4; ++q){
        float2 f = __half22float2(hp1[q]);
        ds_ = fmaf(f.x, att_s[8+2*q], ds_); ds_ = fmaf(f.y, att_s[8+2*q+1], ds_);
        dd_ = fmaf(f.x, att_d[8+2*q], dd_); dd_ = fmaf(f.y, att_d[8+2*q+1], dd_);
    }
    a_src[n] = ds_;
    a_dst[n] = dd_;
}

// ---------------- node-centric aggregation (no-max softmax: e bounded) ----------------

// one wave per node; lane = h*8+c; unroll-8, wave-uniform scalar esrc loads
__global__ __launch_bounds__(256) void layer1_node(const int* __restrict__ rowstart,
        const int* __restrict__ esrc, const float* __restrict__ a_src,
        const float* __restrict__ a_dst, const __half* __restrict__ h1h,
        const float* __restrict__ b1, float* __restrict__ out1){
    int wid = __builtin_amdgcn_readfirstlane((blockIdx.x*256 + threadIdx.x) >> 6);
    int lane = threadIdx.x & 63;
    if (wid >= NN) return;
    int n = wid;
    int h = lane >> 3;
    int r0 = rowstart[n], r1 = rowstart[n+1];
    float ad = a_dst[n*8 + h];
    float den0 = 0.f, acc0 = 0.f, den1 = 0.f, acc1 = 0.f;
    float den2 = 0.f, acc2 = 0.f, den3 = 0.f, acc3 = 0.f;
    float den4 = 0.f, acc4 = 0.f, den5 = 0.f, acc5 = 0.f;
    float den6 = 0.f, acc6 = 0.f, den7 = 0.f, acc7 = 0.f;
    int i = r0;
    for (; i + 7 < r1; i += 8){
        int s0 = esrc[i],   s1 = esrc[i+1], s2 = esrc[i+2], s3 = esrc[i+3];
        int s4 = esrc[i+4], s5 = esrc[i+5], s6 = esrc[i+6], s7 = esrc[i+7];
        float e0 = leaky(a_src[s0*8 + h] + ad);
        float e1 = leaky(a_src[s1*8 + h] + ad);
        float e2 = leaky(a_src[s2*8 + h] + ad);
        float e3 = leaky(a_src[s3*8 + h] + ad);
        float e4 = leaky(a_src[s4*8 + h] + ad);
        float e5 = leaky(a_src[s5*8 + h] + ad);
        float e6 = leaky(a_src[s6*8 + h] + ad);
        float e7 = leaky(a_src[s7*8 + h] + ad);
        float hv0 = __half2float(h1h[s0*64 + lane]);
        float hv1 = __half2float(h1h[s1*64 + lane]);
        float hv2 = __half2float(h1h[s2*64 + lane]);
        float hv3 = __half2float(h1h[s3*64 + lane]);
        float hv4 = __half2float(h1h[s4*64 + lane]);
        float hv5 = __half2float(h1h[s5*64 + lane]);
        float hv6 = __half2float(h1h[s6*64 + lane]);
        float hv7 = __half2float(h1h[s7*64 + lane]);
        float p0 = __expf(e0), p1 = __expf(e1), p2 = __expf(e2), p3 = __expf(e3);
        float p4 = __expf(e4), p5 = __expf(e5), p6 = __expf(e6), p7 = __expf(e7);
        den0 += p0; acc0 = fmaf(p0, hv0, acc0);
        den1 += p1; acc1 = fmaf(p1, hv1, acc1);
        den2 += p2; acc2 = fmaf(p2, hv2, acc2);
        den3 += p3; acc3 = fmaf(p3, hv3, acc3);
        den4 += p4; acc4 = fmaf(p4, hv4, acc4);
        den5 += p5; acc5 = fmaf(p5, hv5, acc5);
        den6 += p6; acc6 = fmaf(p6, hv6, acc6);
        den7 += p7; acc7 = fmaf(p7, hv7, acc7);
    }
    for (; i + 3 < r1; i += 4){
        int s0 = esrc[i], s1 = esrc[i+1], s2 = esrc[i+2], s3 = esrc[i+3];
        float e0 = leaky(a_src[s0*8 + h] + ad);
        float e1 = leaky(a_src[s1*8 + h] + ad);
        float e2 = leaky(a_src[s2*8 + h] + ad);
        float e3 = leaky(a_src[s3*8 + h] + ad);
        float hv0 = __half2float(h1h[s0*64 + lane]);
        float hv1 = __half2float(h1h[s1*64 + lane]);
        float hv2 = __half2float(h1h[s2*64 + lane]);
        float hv3 = __half2float(h1h[s3*64 + lane]);
        float p0 = __expf(e0), p1 = __expf(e1), p2 = __expf(e2), p3 = __expf(e3);
        den0 += p0; acc0 = fmaf(p0, hv0, acc0);
        den1 += p1; acc1 = fmaf(p1, hv1, acc1);
        den2 += p2; acc2 = fmaf(p2, hv2, acc2);
        den3 += p3; acc3 = fmaf(p3, hv3, acc3);
    }
    for (; i < r1; ++i){
        int s = esrc[i];
        float p = __expf(leaky(a_src[s*8 + h] + ad));
        den0 += p; acc0 = fmaf(p, __half2float(h1h[s*64 + lane]), acc0);
    }
    float den = ((den0 + den1) + (den2 + den3)) + ((den4 + den5) + (den6 + den7));
    float acc = ((acc0 + acc1) + (acc2 + acc3)) + ((acc4 + acc5) + (acc6 + acc7));
    out1[n*64 + lane] = acc/(den + 1e-16f) + b1[lane];
}

// one wave per node; lane = slot*16 + c; 4 slots x unroll-4 = 16 edges in flight
__global__ __launch_bounds__(256) void layer2_node(const int* __restrict__ rowstart,
        const int* __restrict__ esrc, const float* __restrict__ a_src,
        const float* __restrict__ a_dst, const __half* __restrict__ h2h,
        const float* __restrict__ b2, float* __restrict__ out){
    int wid = __builtin_amdgcn_readfirstlane((blockIdx.x*256 + threadIdx.x) >> 6);
    int lane = threadIdx.x & 63;
    if (wid >= NN) return;
    int n = wid;
    int slot = lane >> 4, c = lane & 15;
    int r0 = rowstart[n], r1 = rowstart[n+1];
    float ad = a_dst[n];
    float den0 = 0.f, acc0 = 0.f, den1 = 0.f, acc1 = 0.f;
    float den2 = 0.f, acc2 = 0.f, den3 = 0.f, acc3 = 0.f;
    int i = r0 + slot;
    for (; i + 12 < r1; i += 16){
        int s0 = esrc[i], s1 = esrc[i+4], s2 = esrc[i+8], s3 = esrc[i+12];
        float p0 = __expf(leaky(a_src[s0] + ad));
        float p1 = __expf(leaky(a_src[s1] + ad));
        float p2 = __expf(leaky(a_src[s2] + ad));
        float p3 = __expf(leaky(a_src[s3] + ad));
        float hv0 = __half2float(h2h[s0*16 + c]);
        float hv1 = __half2float(h2h[s1*16 + c]);
        float hv2 = __half2float(h2h[s2*16 + c]);
        float hv3 = __half2float(h2h[s3*16 + c]);
        den0 += p0; acc0 = fmaf(p0, hv0, acc0);
        den1 += p1; acc1 = fmaf(p1, hv1, acc1);
        den2 += p2; acc2 = fmaf(p2, hv2, acc2);
        den3 += p3; acc3 = fmaf(p3, hv3, acc3);
    }
    for (; i < r1; i += 4){
        int s = esrc[i];
        float p = __expf(leaky(a_src[s] + ad));
        den0 += p; acc0 = fmaf(p, __half2float(h2h[s*16 + c]), acc0);
    }
    float den = (den0 + den1) + (den2 + den3);
    float acc = (acc0 + acc1) + (acc2 + acc3);
    den += __shfl_xor(den, 16); den += __shfl_xor(den, 32);
    acc += __shfl_xor(acc, 16); acc += __shfl_xor(acc, 32);
    if (slot == 0) out[n*16 + c] = acc/(den + 1e-16f) + b2[c];
}

extern "C" void kernel_launch(void* const* d_in, const int* in_sizes, int n_in,
                              void* d_out, int out_size, void* d_ws, size_t ws_size,
                              hipStream_t stream){
    const float* x    = (const float*)d_in[0];
    const int*   ei   = (const int*)d_in[1];
    const float* W1   = (const float*)d_in[2];
    const float* as1w = (const float*)d_in[3];
    const float* ad1w = (const float*)d_in[4];
    const float* b1   = (const float*)d_in[5];
    const float* W2   = (const float*)d_in[6];
    const float* as2w = (const float*)d_in[7];
    const float* ad2w = (const float*)d_in[8];
    const float* b2   = (const float*)d_in[9];
    float* out = (float*)d_out;

    float* ws = (float*)d_ws;
    // words: h1h 32N | out1 64N | rowstart N+1 | gbcnt NBUK | gboff NBUK+1 | gbcur NBUK |
    //        packed ETOT | esrc ETOT  (~25.9 MB)
    __half* h1h     = (__half*)ws;                      // 64N halves = 32N words
    float* out1     = ws + (size_t)32*NN;               // 64N
    int*   rowstart = (int*)(ws + (size_t)96*NN);       // N+1
    int*   gbcnt    = rowstart + NN + 1;                // NBUK
    int*   gboff    = gbcnt + NBUK;                     // NBUK+1
    int*   gbcur    = gboff + NBUK + 1;                 // NBUK
    unsigned* packed= (unsigned*)(gbcur + NBUK);        // ETOT
    int*   esrc     = (int*)(packed + ETOT);            // ETOT
    // a_src1/a_dst1 live in d_out (16N floats) until layer1_node; layer2_node overwrites d_out last
    float* a_src1 = out;                                // 8N
    float* a_dst1 = out + (size_t)8*NN;                 // 8N
    __half* h2h   = h1h;                                // 16N halves (h1h dead after layer1_node)
    float* a_src2 = ws + (size_t)8*NN;                  // N (after h2h's 8N words)
    float* a_dst2 = a_src2 + NN;                        // N

    // CSR build via two-level binning
    hipLaunchKernelGGL(zero_gbcnt,      dim3(2), dim3(256), 0, stream, gbcnt);
    hipLaunchKernelGGL(bucket_hist,     dim3(NBLK_A), dim3(256), 0, stream, ei, gbcnt);
    hipLaunchKernelGGL(bucket_scan,     dim3(1), dim3(512), 0, stream, gbcnt, gboff, gbcur);
    hipLaunchKernelGGL(bucket_scatter,  dim3(NBLK_A), dim3(256), 0, stream, ei, gbcur, packed);
    hipLaunchKernelGGL(bucket_finalize, dim3(NBUK), dim3(256), 0, stream, packed, gboff, rowstart, esrc);

    // layer 1
    hipLaunchKernelGGL(gemm1, dim3((NN + 63)/64), dim3(256), 0, stream, x, W1, h1h);
    hipLaunchKernelGGL(att1,  dim3((NN*NH + 255)/256), dim3(256), 0, stream, h1h, as1w, ad1w, a_src1, a_dst1);
    hipLaunchKernelGGL(layer1_node, dim3((NN*64 + 255)/256), dim3(256), 0, stream,
                       rowstart, esrc, a_src1, a_dst1, h1h, b1, out1);
    // layer 2
    hipLaunchKernelGGL(gemm2, dim3((NN + 63)/64), dim3(256), 0, stream, out1, W2, h2h);
    hipLaunchKernelGGL(att2,  dim3((NN + 255)/256), dim3(256), 0, stream, h2h, as2w, ad2w, a_src2, a_dst2);
    hipLaunchKernelGGL(layer2_node, dim3((NN*64 + 255)/256), dim3(256), 0, stream,
                       rowstart, esrc, a_src2, a_dst2, h2h, b2, out);
}